// Round 2
// baseline (512.299 us; speedup 1.0000x reference)
//
#include <hip/hip_runtime.h>
#include <hip/hip_bf16.h>
#include <math.h>

#define B_ 2
#define T_ 2048
#define E_ 1024
#define H_ 16
#define D_ 64
#define MTOK (B_*T_)   // 4096

typedef __bf16 bf16;
typedef __bf16 bf16x8 __attribute__((ext_vector_type(8)));
typedef float  f32x4  __attribute__((ext_vector_type(4)));

__device__ __forceinline__ void gl_lds16(const void* g, void* l) {
    __builtin_amdgcn_global_load_lds(
        (const __attribute__((address_space(1))) void*)g,
        (__attribute__((address_space(3))) void*)l, 16, 0, 0);
}

// ---------------- f32 -> bf16 hi/lo split elementwise ----------------
__global__ __launch_bounds__(256) void f2b_split_kernel(const float* __restrict__ s,
                                                        bf16* __restrict__ hi,
                                                        bf16* __restrict__ lo, int n) {
    int i = (blockIdx.x * 256 + threadIdx.x) * 4;
    if (i + 3 < n) {
        float4 v = *(const float4*)(s + i);
        float vv[4] = {v.x, v.y, v.z, v.w};
#pragma unroll
        for (int j = 0; j < 4; ++j) {
            bf16 h = (bf16)vv[j];
            hi[i+j] = h;
            lo[i+j] = (bf16)(vv[j] - (float)h);
        }
    }
}

// ---------------- W [K,N] f32 -> W^T [N,K] bf16 (plain) ----------------
__global__ void tconv_kernel(const float* __restrict__ src, bf16* __restrict__ dst,
                             int rows, int cols) {
    __shared__ float t[32][33];
    int nbx = cols >> 5;
    int bx = blockIdx.x % nbx, by = blockIdx.x / nbx;
    int tx = threadIdx.x, ty = threadIdx.y;
#pragma unroll
    for (int i = ty; i < 32; i += 8)
        t[i][tx] = src[(size_t)(by*32 + i)*cols + bx*32 + tx];
    __syncthreads();
#pragma unroll
    for (int i = ty; i < 32; i += 8)
        dst[(size_t)(bx*32 + i)*rows + by*32 + tx] = (bf16)t[tx][i];
}

// ---------------- W [K,N] f32 -> W^T [N,K] bf16 hi/lo split ----------------
__global__ void tconv_split_kernel(const float* __restrict__ src,
                                   bf16* __restrict__ dh, bf16* __restrict__ dl,
                                   int rows, int cols) {
    __shared__ float t[32][33];
    int nbx = cols >> 5;
    int bx = blockIdx.x % nbx, by = blockIdx.x / nbx;
    int tx = threadIdx.x, ty = threadIdx.y;
#pragma unroll
    for (int i = ty; i < 32; i += 8)
        t[i][tx] = src[(size_t)(by*32 + i)*cols + bx*32 + tx];
    __syncthreads();
#pragma unroll
    for (int i = ty; i < 32; i += 8) {
        float v = t[tx][i];
        bf16 h = (bf16)v;
        size_t idx = (size_t)(bx*32 + i)*rows + by*32 + tx;
        dh[idx] = h;
        dl[idx] = (bf16)(v - (float)h);
    }
}

// ---------------- plain GEMM: C[M,N] f32 = A[M,K]bf16 @ BT[N,K]bf16 ----------------
__global__ __launch_bounds__(256) void gemm_bf16_kernel(
    const bf16* __restrict__ A, const bf16* __restrict__ BT, float* __restrict__ C,
    int M, int N, int K) {
    __shared__ __align__(16) bf16 As[128*32];
    __shared__ __align__(16) bf16 Bs[128*32];
    const int nbx = N >> 7;
    const int bx = blockIdx.x % nbx, by = blockIdx.x / nbx;
    const int tid = threadIdx.x, lane = tid & 63, wid = tid >> 6;
    const int wr = wid >> 1, wc = wid & 1;       // 2x2 waves, 64x64 each
    f32x4 acc[4][4];
#pragma unroll
    for (int m = 0; m < 4; ++m)
#pragma unroll
        for (int n = 0; n < 4; ++n) acc[m][n] = (f32x4)0.0f;
    const int tr = tid >> 2;          // staging row within 64-row half
    const int tc = (tid & 3) * 8;     // staging col (elems)
    for (int k0 = 0; k0 < K; k0 += 32) {
#pragma unroll
        for (int i = 0; i < 2; ++i) {
            gl_lds16(A  + (size_t)(by*128 + i*64 + tr)*K + k0 + tc, &As[(i*256 + wid*64)*8]);
            gl_lds16(BT + (size_t)(bx*128 + i*64 + tr)*K + k0 + tc, &Bs[(i*256 + wid*64)*8]);
        }
        __syncthreads();
        bf16x8 af[4], bfr[4];
#pragma unroll
        for (int m = 0; m < 4; ++m)
            af[m] = *(const bf16x8*)&As[(wr*64 + m*16 + (lane&15))*32 + ((lane>>4)*8)];
#pragma unroll
        for (int n = 0; n < 4; ++n)
            bfr[n] = *(const bf16x8*)&Bs[(wc*64 + n*16 + (lane&15))*32 + ((lane>>4)*8)];
#pragma unroll
        for (int m = 0; m < 4; ++m)
#pragma unroll
            for (int n = 0; n < 4; ++n)
                acc[m][n] = __builtin_amdgcn_mfma_f32_16x16x32_bf16(af[m], bfr[n], acc[m][n], 0, 0, 0);
        __syncthreads();
    }
    const int crow = by*128 + wr*64;
    const int ccol = bx*128 + wc*64 + (lane & 15);
#pragma unroll
    for (int m = 0; m < 4; ++m)
#pragma unroll
        for (int r = 0; r < 4; ++r) {
            int row = crow + m*16 + (lane>>4)*4 + r;
#pragma unroll
            for (int n = 0; n < 4; ++n)
                C[(size_t)row*N + ccol + n*16] = acc[m][n][r];
        }
}

// ---------------- split GEMM: C f32 = (Ah+Al)(Bh+Bl)^T, 3 cross products ----------------
__global__ __launch_bounds__(256) void gemm_split_kernel(
    const bf16* __restrict__ Ah, const bf16* __restrict__ Al,
    const bf16* __restrict__ Bh, const bf16* __restrict__ Bl,
    float* __restrict__ C, int M, int N, int K) {
    __shared__ __align__(16) bf16 Ash[128*32];
    __shared__ __align__(16) bf16 Asl[128*32];
    __shared__ __align__(16) bf16 Bsh[128*32];
    __shared__ __align__(16) bf16 Bsl[128*32];
    const int nbx = N >> 7;
    const int bx = blockIdx.x % nbx, by = blockIdx.x / nbx;
    const int tid = threadIdx.x, lane = tid & 63, wid = tid >> 6;
    const int wr = wid >> 1, wc = wid & 1;
    f32x4 acc[4][4];
#pragma unroll
    for (int m = 0; m < 4; ++m)
#pragma unroll
        for (int n = 0; n < 4; ++n) acc[m][n] = (f32x4)0.0f;
    const int tr = tid >> 2;
    const int tc = (tid & 3) * 8;
    for (int k0 = 0; k0 < K; k0 += 32) {
#pragma unroll
        for (int i = 0; i < 2; ++i) {
            size_t ga = (size_t)(by*128 + i*64 + tr)*K + k0 + tc;
            size_t gb = (size_t)(bx*128 + i*64 + tr)*K + k0 + tc;
            gl_lds16(Ah + ga, &Ash[(i*256 + wid*64)*8]);
            gl_lds16(Al + ga, &Asl[(i*256 + wid*64)*8]);
            gl_lds16(Bh + gb, &Bsh[(i*256 + wid*64)*8]);
            gl_lds16(Bl + gb, &Bsl[(i*256 + wid*64)*8]);
        }
        __syncthreads();
        bf16x8 ah[4], al[4], bh[4], bl[4];
#pragma unroll
        for (int m = 0; m < 4; ++m) {
            int o = (wr*64 + m*16 + (lane&15))*32 + ((lane>>4)*8);
            ah[m] = *(const bf16x8*)&Ash[o];
            al[m] = *(const bf16x8*)&Asl[o];
        }
#pragma unroll
        for (int n = 0; n < 4; ++n) {
            int o = (wc*64 + n*16 + (lane&15))*32 + ((lane>>4)*8);
            bh[n] = *(const bf16x8*)&Bsh[o];
            bl[n] = *(const bf16x8*)&Bsl[o];
        }
#pragma unroll
        for (int m = 0; m < 4; ++m)
#pragma unroll
            for (int n = 0; n < 4; ++n) {
                acc[m][n] = __builtin_amdgcn_mfma_f32_16x16x32_bf16(al[m], bh[n], acc[m][n], 0, 0, 0);
                acc[m][n] = __builtin_amdgcn_mfma_f32_16x16x32_bf16(ah[m], bl[n], acc[m][n], 0, 0, 0);
                acc[m][n] = __builtin_amdgcn_mfma_f32_16x16x32_bf16(ah[m], bh[n], acc[m][n], 0, 0, 0);
            }
        __syncthreads();
    }
    const int crow = by*128 + wr*64;
    const int ccol = bx*128 + wc*64 + (lane & 15);
#pragma unroll
    for (int m = 0; m < 4; ++m)
#pragma unroll
        for (int r = 0; r < 4; ++r) {
            int row = crow + m*16 + (lane>>4)*4 + r;
#pragma unroll
            for (int n = 0; n < 4; ++n)
                C[(size_t)row*N + ccol + n*16] = acc[m][n][r];
        }
}

// ---------------- per-(token,head) L2 normalize -> bf16 hi/lo ----------------
__global__ __launch_bounds__(256) void qknorm_split_kernel(const float* __restrict__ src,
                                                           bf16* __restrict__ dh,
                                                           bf16* __restrict__ dl) {
    int row  = blockIdx.x * 4 + (threadIdx.x >> 6);
    int lane = threadIdx.x & 63;
    float v = src[(size_t)row*64 + lane];
    float ss = v * v;
#pragma unroll
    for (int off = 1; off < 64; off <<= 1) ss += __shfl_xor(ss, off, 64);
    float nrm = fmaxf(sqrtf(ss), 1e-12f);
    float q = v / nrm;
    bf16 h = (bf16)q;
    dh[(size_t)row*64 + lane] = h;
    dl[(size_t)row*64 + lane] = (bf16)(q - (float)h);
}

// ---------------- V f32 [B,T,H,D] -> bf16 V^T [(b*H+h)*D + d][T] ----------------
__global__ __launch_bounds__(256) void vtrans_kernel(const float* __restrict__ src,
                                                     bf16* __restrict__ dst) {
    const int ntt = T_/32;
    int tt = blockIdx.x % ntt, bh = blockIdx.x / ntt;
    int b = bh / H_, h = bh % H_;
    int t0 = tt * 32;
    __shared__ float tile[32][65];
    int lane = threadIdx.x & 63, g = threadIdx.x >> 6;
    for (int i = g; i < 32; i += 4)
        tile[i][lane] = src[((size_t)(b*T_ + t0 + i)*H_ + h)*64 + lane];
    __syncthreads();
    int d = threadIdx.x >> 2, c0 = (threadIdx.x & 3) * 8;
    __align__(16) bf16 e[8];
#pragma unroll
    for (int j = 0; j < 8; ++j) e[j] = (bf16)tile[c0 + j][d];
    *(bf16x8*)(dst + (size_t)(bh*64 + d)*T_ + t0 + c0) = *(const bf16x8*)e;
}

// ---------------- dt -> log(alpha + 1e-8) per (b,h,t) ----------------
__global__ __launch_bounds__(256) void dt_kernel(const float* __restrict__ x,
                                                 const float* __restrict__ Wa,
                                                 const float* __restrict__ A_log,
                                                 const float* __restrict__ dt_bias,
                                                 float* __restrict__ lg) {
    int n = blockIdx.x;            // token index b*T + t
    int tid = threadIdx.x;
    int h = tid >> 4, p = tid & 15;
    const float* xr = x + (size_t)n*E_;
    float s = 0.f;
    for (int k = p*64; k < p*64 + 64; ++k) s += xr[k] * Wa[k*H_ + h];
#pragma unroll
    for (int off = 1; off < 16; off <<= 1) s += __shfl_xor(s, off, 64);
    if (p == 0) {
        float z   = s + dt_bias[h];
        float dtv = (z > 20.f) ? z : log1pf(expf(z));
        float la  = -expf(A_log[h]) * dtv;
        float alpha = expf(la);
        float l   = logf(alpha + 1e-8f);
        int b = n / T_, t = n % T_;
        lg[(size_t)(b*H_ + h)*T_ + t] = l;
    }
}

// ---------------- f64 inclusive scan of lg rows -> cl ----------------
__global__ __launch_bounds__(256) void scan_kernel(const float* __restrict__ lg,
                                                   double* __restrict__ cl) {
    int row = blockIdx.x, tid = threadIdx.x;
    __shared__ double ls[256];
    const float* p = lg + (size_t)row*T_ + tid*8;
    double loc[8], s = 0.0;
#pragma unroll
    for (int j = 0; j < 8; ++j) { s += (double)p[j]; loc[j] = s; }
    ls[tid] = s;
    __syncthreads();
    for (int off = 1; off < 256; off <<= 1) {
        double add = (tid >= off) ? ls[tid - off] : 0.0;
        __syncthreads();
        ls[tid] += add;
        __syncthreads();
    }
    double prefix = ls[tid] - s;   // exclusive prefix of this thread's chunk
    double* o = cl + (size_t)row*T_ + tid*8;
#pragma unroll
    for (int j = 0; j < 8; ++j) o[j] = prefix + loc[j];
}

// ---------------- decay attention + RMSNorm + SiLU gate -> Y bf16 ----------------
__global__ __launch_bounds__(256) void attn_kernel(
    const bf16* __restrict__ qh, const bf16* __restrict__ ql,
    const bf16* __restrict__ kh, const bf16* __restrict__ kl,
    const bf16* __restrict__ vt,
    const double* __restrict__ cl, const float* __restrict__ G,
    const float* __restrict__ rms_w, bf16* __restrict__ Y) {
    __shared__ __align__(16) bf16 Ksh[64*64];  // [key][d] hi
    __shared__ __align__(16) bf16 Ksl[64*64];  // [key][d] lo
    __shared__ __align__(16) bf16 Vs[64*64];   // [d][key]
    __shared__ __align__(16) bf16 Ps[64*64];   // [row][key]
    const int nqt = T_/64;
    const int it = blockIdx.x % nqt, bh = blockIdx.x / nqt;
    const int b = bh / H_, h = bh % H_;
    const int tid = threadIdx.x, lane = tid & 63, wid = tid >> 6;
    const int i0 = it * 64;
    // Q fragments hi/lo (wave wid owns rows i0+wid*16 .. +16)
    const size_t qoff = (size_t)(b*T_ + i0 + wid*16 + (lane&15))*D_ + ((lane>>4)*8);
    // note: qh/ql laid out [row65536][64] with row = token*H + h handled below
    const size_t qrow = (size_t)((b*T_ + i0 + wid*16 + (lane&15))*H_ + h)*D_ + ((lane>>4)*8);
    const bf16x8 qh0 = *(const bf16x8*)(qh + qrow);
    const bf16x8 qh1 = *(const bf16x8*)(qh + qrow + 32);
    const bf16x8 ql0 = *(const bf16x8*)(ql + qrow);
    const bf16x8 ql1 = *(const bf16x8*)(ql + qrow + 32);
    const int irow = i0 + wid*16 + ((lane>>4)*4);
    double cli[4];
#pragma unroll
    for (int r = 0; r < 4; ++r) cli[r] = cl[(size_t)bh*T_ + irow + r];
    f32x4 oacc[4];
#pragma unroll
    for (int n = 0; n < 4; ++n) oacc[n] = (f32x4)0.0f;
    const int sr = tid >> 3;          // staging row within 32-row half
    const int sc = (tid & 7) * 8;     // staging col (elems)
    for (int j0 = 0; j0 <= i0; j0 += 64) {
#pragma unroll
        for (int i = 0; i < 2; ++i) {
            size_t gk = (size_t)((b*T_ + j0 + i*32 + sr)*H_ + h)*D_ + sc;
            gl_lds16(kh + gk, &Ksh[(i*256 + wid*64)*8]);
            gl_lds16(kl + gk, &Ksl[(i*256 + wid*64)*8]);
            gl_lds16(vt + (size_t)(bh*64 + i*32 + sr)*T_ + j0 + sc, &Vs[(i*256 + wid*64)*8]);
        }
        __syncthreads();
        // S = (qh+ql)(kh+kl)^T via 3 cross products, decay+mask, write P
#pragma unroll
        for (int n = 0; n < 4; ++n) {
            f32x4 s = (f32x4)0.0f;
            int ko = (n*16 + (lane&15))*64 + ((lane>>4)*8);
            bf16x8 kh0 = *(const bf16x8*)&Ksh[ko];
            bf16x8 kh1 = *(const bf16x8*)&Ksh[ko + 32];
            bf16x8 kl0 = *(const bf16x8*)&Ksl[ko];
            bf16x8 kl1 = *(const bf16x8*)&Ksl[ko + 32];
            s = __builtin_amdgcn_mfma_f32_16x16x32_bf16(ql0, kh0, s, 0, 0, 0);
            s = __builtin_amdgcn_mfma_f32_16x16x32_bf16(ql1, kh1, s, 0, 0, 0);
            s = __builtin_amdgcn_mfma_f32_16x16x32_bf16(qh0, kl0, s, 0, 0, 0);
            s = __builtin_amdgcn_mfma_f32_16x16x32_bf16(qh1, kl1, s, 0, 0, 0);
            s = __builtin_amdgcn_mfma_f32_16x16x32_bf16(qh0, kh0, s, 0, 0, 0);
            s = __builtin_amdgcn_mfma_f32_16x16x32_bf16(qh1, kh1, s, 0, 0, 0);
            const int j = j0 + n*16 + (lane & 15);
            const double clj = cl[(size_t)bh*T_ + j];
#pragma unroll
            for (int r = 0; r < 4; ++r) {
                float val = 0.0f;
                if (j <= irow + r) val = s[r] * __expf((float)(cli[r] - clj));
                Ps[(wid*16 + (lane>>4)*4 + r)*64 + n*16 + (lane&15)] = (bf16)val;
            }
        }
        // O += P V
#pragma unroll
        for (int kk = 0; kk < 2; ++kk) {
            bf16x8 pf = *(const bf16x8*)&Ps[(wid*16 + (lane&15))*64 + kk*32 + ((lane>>4)*8)];
#pragma unroll
            for (int n = 0; n < 4; ++n) {
                bf16x8 vf = *(const bf16x8*)&Vs[(n*16 + (lane&15))*64 + kk*32 + ((lane>>4)*8)];
                oacc[n] = __builtin_amdgcn_mfma_f32_16x16x32_bf16(pf, vf, oacc[n], 0, 0, 0);
            }
        }
        __syncthreads();
    }
    // epilogue: RMSNorm over d=64, * rms_w, * silu(gate), -> bf16 Y
#pragma unroll
    for (int r = 0; r < 4; ++r) {
        float ss = oacc[0][r]*oacc[0][r] + oacc[1][r]*oacc[1][r]
                 + oacc[2][r]*oacc[2][r] + oacc[3][r]*oacc[3][r];
#pragma unroll
        for (int off = 1; off < 16; off <<= 1) ss += __shfl_xor(ss, off, 64);
        const float scale = rsqrtf(ss * (1.0f/64.0f) + 1e-6f);
        const int ig = irow + r;
#pragma unroll
        for (int n = 0; n < 4; ++n) {
            const int d = n*16 + (lane & 15);
            float o = oacc[n][r] * scale * rms_w[d];
            float g = G[(size_t)(b*T_ + ig)*E_ + h*64 + d];
            float gate = g / (1.0f + __expf(-g));
            Y[(size_t)(b*T_ + ig)*E_ + h*64 + d] = (bf16)(o * gate);
        }
    }
}

extern "C" void kernel_launch(void* const* d_in, const int* in_sizes, int n_in,
                              void* d_out, int out_size, void* d_ws, size_t ws_size,
                              hipStream_t stream) {
    const float* x       = (const float*)d_in[0];
    const float* Wq      = (const float*)d_in[1];
    const float* Wk      = (const float*)d_in[2];
    const float* Wv      = (const float*)d_in[3];
    const float* Wa      = (const float*)d_in[4];
    const float* Wg      = (const float*)d_in[5];
    const float* Wo      = (const float*)d_in[6];
    const float* A_log   = (const float*)d_in[7];
    const float* dt_bias = (const float*)d_in[8];
    const float* rms_w   = (const float*)d_in[9];
    float* out = (float*)d_out;

    char* w = (char*)d_ws;
    size_t off = 0;
    auto alloc = [&](size_t bytes) {
        void* p = w + off; off += (bytes + 255) & ~(size_t)255; return p;
    };
    bf16*   xh  = (bf16*)  alloc((size_t)MTOK*E_*2);
    bf16*   xl  = (bf16*)  alloc((size_t)MTOK*E_*2);
    bf16*   WTh = (bf16*)  alloc((size_t)E_*E_*2);
    bf16*   WTl = (bf16*)  alloc((size_t)E_*E_*2);
    float*  tmp = (float*) alloc((size_t)MTOK*E_*4);
    float*  Gf  = (float*) alloc((size_t)MTOK*E_*4);
    bf16*   qhb = (bf16*)  alloc((size_t)MTOK*E_*2);
    bf16*   qlb = (bf16*)  alloc((size_t)MTOK*E_*2);
    bf16*   khb = (bf16*)  alloc((size_t)MTOK*E_*2);
    bf16*   klb = (bf16*)  alloc((size_t)MTOK*E_*2);
    bf16*   vt  = (bf16*)  alloc((size_t)MTOK*E_*2);
    float*  lg  = (float*) alloc((size_t)B_*H_*T_*4);
    double* cl  = (double*)alloc((size_t)B_*H_*T_*8);
    bf16*   Yb  = (bf16*)  alloc((size_t)MTOK*E_*2);

    dim3 tb(32, 8);
    const int gemmGrid = (MTOK/128) * (E_/128);   // 256

    hipLaunchKernelGGL(f2b_split_kernel, dim3(MTOK*E_/1024), dim3(256), 0, stream, x, xh, xl, MTOK*E_);
    hipLaunchKernelGGL(dt_kernel,  dim3(MTOK), dim3(256), 0, stream, x, Wa, A_log, dt_bias, lg);
    hipLaunchKernelGGL(scan_kernel, dim3(B_*H_), dim3(256), 0, stream, lg, cl);

    // Q (split precision)
    hipLaunchKernelGGL(tconv_split_kernel, dim3(1024), tb, 0, stream, Wq, WTh, WTl, E_, E_);
    hipLaunchKernelGGL(gemm_split_kernel, dim3(gemmGrid), dim3(256), 0, stream,
                       xh, xl, WTh, WTl, tmp, MTOK, E_, E_);
    hipLaunchKernelGGL(qknorm_split_kernel, dim3(MTOK*H_/4), dim3(256), 0, stream, tmp, qhb, qlb);
    // K (split precision)
    hipLaunchKernelGGL(tconv_split_kernel, dim3(1024), tb, 0, stream, Wk, WTh, WTl, E_, E_);
    hipLaunchKernelGGL(gemm_split_kernel, dim3(gemmGrid), dim3(256), 0, stream,
                       xh, xl, WTh, WTl, tmp, MTOK, E_, E_);
    hipLaunchKernelGGL(qknorm_split_kernel, dim3(MTOK*H_/4), dim3(256), 0, stream, tmp, khb, klb);
    // V (plain, transposed to [(b h d)][t])
    hipLaunchKernelGGL(tconv_kernel, dim3(1024), tb, 0, stream, Wv, WTh, E_, E_);
    hipLaunchKernelGGL(gemm_bf16_kernel, dim3(gemmGrid), dim3(256), 0, stream, xh, WTh, tmp, MTOK, E_, E_);
    hipLaunchKernelGGL(vtrans_kernel, dim3(B_*H_*(T_/32)), dim3(256), 0, stream, tmp, vt);
    // Gate (pre-silu, plain)
    hipLaunchKernelGGL(tconv_kernel, dim3(1024), tb, 0, stream, Wg, WTh, E_, E_);
    hipLaunchKernelGGL(gemm_bf16_kernel, dim3(gemmGrid), dim3(256), 0, stream, xh, WTh, Gf, MTOK, E_, E_);
    // Attention + RMSNorm + gate
    hipLaunchKernelGGL(attn_kernel, dim3(B_*H_*(T_/64)), dim3(256), 0, stream,
                       qhb, qlb, khb, klb, vt, cl, Gf, rms_w, Yb);
    // Output projection -> d_out (f32)
    hipLaunchKernelGGL(tconv_kernel, dim3(1024), tb, 0, stream, Wo, WTh, E_, E_);
    hipLaunchKernelGGL(gemm_bf16_kernel, dim3(gemmGrid), dim3(256), 0, stream, Yb, WTh, out, MTOK, E_, E_);
}

// Round 4
// 358.477 us; speedup vs baseline: 1.4291x; 1.4291x over previous
//
#include <hip/hip_runtime.h>
#include <hip/hip_bf16.h>
#include <math.h>

#define B_ 2
#define T_ 2048
#define E_ 1024
#define H_ 16
#define D_ 64
#define MTOK (B_*T_)   // 4096

typedef __bf16 bf16;
typedef __bf16 bf16x8 __attribute__((ext_vector_type(8)));
typedef __bf16 bf16x4 __attribute__((ext_vector_type(4)));
typedef float  f32x4  __attribute__((ext_vector_type(4)));

__device__ __forceinline__ void gl_lds16(const void* g, void* l) {
    __builtin_amdgcn_global_load_lds(
        (const __attribute__((address_space(1))) void*)g,
        (__attribute__((address_space(3))) void*)l, 16, 0, 0);
}

// ---------------- f32 -> bf16 hi/lo split elementwise ----------------
__global__ __launch_bounds__(256) void f2b_split_kernel(const float* __restrict__ s,
                                                        bf16* __restrict__ hi,
                                                        bf16* __restrict__ lo, int n) {
    int i = (blockIdx.x * 256 + threadIdx.x) * 4;
    if (i + 3 < n) {
        float4 v = *(const float4*)(s + i);
        float vv[4] = {v.x, v.y, v.z, v.w};
#pragma unroll
        for (int j = 0; j < 4; ++j) {
            bf16 h = (bf16)vv[j];
            hi[i+j] = h;
            lo[i+j] = (bf16)(vv[j] - (float)h);
        }
    }
}

// ---------------- W [K,N] f32 -> W^T [N,K] bf16 (plain) ----------------
__global__ void tconv_kernel(const float* __restrict__ src, bf16* __restrict__ dst,
                             int rows, int cols) {
    __shared__ float t[32][33];
    int nbx = cols >> 5;
    int bx = blockIdx.x % nbx, by = blockIdx.x / nbx;
    int tx = threadIdx.x, ty = threadIdx.y;
#pragma unroll
    for (int i = ty; i < 32; i += 8)
        t[i][tx] = src[(size_t)(by*32 + i)*cols + bx*32 + tx];
    __syncthreads();
#pragma unroll
    for (int i = ty; i < 32; i += 8)
        dst[(size_t)(bx*32 + i)*rows + by*32 + tx] = (bf16)t[tx][i];
}

// ---------------- W [K,N] f32 -> W^T [N,K] bf16 hi/lo split ----------------
__global__ void tconv_split_kernel(const float* __restrict__ src,
                                   bf16* __restrict__ dh, bf16* __restrict__ dl,
                                   int rows, int cols) {
    __shared__ float t[32][33];
    int nbx = cols >> 5;
    int bx = blockIdx.x % nbx, by = blockIdx.x / nbx;
    int tx = threadIdx.x, ty = threadIdx.y;
#pragma unroll
    for (int i = ty; i < 32; i += 8)
        t[i][tx] = src[(size_t)(by*32 + i)*cols + bx*32 + tx];
    __syncthreads();
#pragma unroll
    for (int i = ty; i < 32; i += 8) {
        float v = t[tx][i];
        bf16 h = (bf16)v;
        size_t idx = (size_t)(bx*32 + i)*rows + by*32 + tx;
        dh[idx] = h;
        dl[idx] = (bf16)(v - (float)h);
    }
}

// ---------------- dt -> log(alpha + 1e-8) per (b,h,t) ----------------
__global__ __launch_bounds__(256) void dt_kernel(const float* __restrict__ x,
                                                 const float* __restrict__ Wa,
                                                 const float* __restrict__ A_log,
                                                 const float* __restrict__ dt_bias,
                                                 float* __restrict__ lg) {
    int n = blockIdx.x;
    int tid = threadIdx.x;
    int h = tid >> 4, p = tid & 15;
    const float* xr = x + (size_t)n*E_;
    float s = 0.f;
    for (int k = p*64; k < p*64 + 64; ++k) s += xr[k] * Wa[k*H_ + h];
#pragma unroll
    for (int off = 1; off < 16; off <<= 1) s += __shfl_xor(s, off, 64);
    if (p == 0) {
        float z   = s + dt_bias[h];
        float dtv = (z > 20.f) ? z : log1pf(expf(z));
        float la  = -expf(A_log[h]) * dtv;
        float alpha = expf(la);
        float l   = logf(alpha + 1e-8f);
        int b = n / T_, t = n % T_;
        lg[(size_t)(b*H_ + h)*T_ + t] = l;
    }
}

// ---------------- f64 inclusive scan of lg rows -> cl ----------------
__global__ __launch_bounds__(256) void scan_kernel(const float* __restrict__ lg,
                                                   double* __restrict__ cl) {
    int row = blockIdx.x, tid = threadIdx.x;
    __shared__ double ls[256];
    const float* p = lg + (size_t)row*T_ + tid*8;
    double loc[8], s = 0.0;
#pragma unroll
    for (int j = 0; j < 8; ++j) { s += (double)p[j]; loc[j] = s; }
    ls[tid] = s;
    __syncthreads();
    for (int off = 1; off < 256; off <<= 1) {
        double add = (tid >= off) ? ls[tid - off] : 0.0;
        __syncthreads();
        ls[tid] += add;
        __syncthreads();
    }
    double prefix = ls[tid] - s;
    double* o = cl + (size_t)row*T_ + tid*8;
#pragma unroll
    for (int j = 0; j < 8; ++j) o[j] = prefix + loc[j];
}

// ---- fused split GEMM (Q|K) N=2048 + L2-norm + hi/lo split epilogue ----
__global__ __launch_bounds__(256) void gemm_qk_kernel(
    const bf16* __restrict__ Ah, const bf16* __restrict__ Al,
    const bf16* __restrict__ Bh, const bf16* __restrict__ Bl,
    bf16* __restrict__ qhb, bf16* __restrict__ qlb,
    bf16* __restrict__ khb, bf16* __restrict__ klb) {
    const int K = E_;
    __shared__ __align__(16) bf16 Ash[128*32];
    __shared__ __align__(16) bf16 Asl[128*32];
    __shared__ __align__(16) bf16 Bsh[128*32];
    __shared__ __align__(16) bf16 Bsl[128*32];
    int bid = blockIdx.x;
    bid = (bid & 7) * 64 + (bid >> 3);           // XCD swizzle, 512 blocks
    const int bx = bid & 15, by = bid >> 4;      // nbx = 2048/128 = 16
    const int tid = threadIdx.x, lane = tid & 63, wid = tid >> 6;
    const int wr = wid >> 1, wc = wid & 1;
    f32x4 acc[4][4];
#pragma unroll
    for (int m = 0; m < 4; ++m)
#pragma unroll
        for (int n = 0; n < 4; ++n) acc[m][n] = (f32x4)0.0f;
    const int tr = tid >> 2;
    const int tc = (tid & 3) * 8;
    for (int k0 = 0; k0 < K; k0 += 32) {
#pragma unroll
        for (int i = 0; i < 2; ++i) {
            size_t ga = (size_t)(by*128 + i*64 + tr)*K + k0 + tc;
            size_t gb = (size_t)(bx*128 + i*64 + tr)*K + k0 + tc;
            gl_lds16(Ah + ga, &Ash[(i*256 + wid*64)*8]);
            gl_lds16(Al + ga, &Asl[(i*256 + wid*64)*8]);
            gl_lds16(Bh + gb, &Bsh[(i*256 + wid*64)*8]);
            gl_lds16(Bl + gb, &Bsl[(i*256 + wid*64)*8]);
        }
        __syncthreads();
        bf16x8 ah[4], al[4], bh[4], bl[4];
#pragma unroll
        for (int m = 0; m < 4; ++m) {
            int o = (wr*64 + m*16 + (lane&15))*32 + ((lane>>4)*8);
            ah[m] = *(const bf16x8*)&Ash[o];
            al[m] = *(const bf16x8*)&Asl[o];
        }
#pragma unroll
        for (int n = 0; n < 4; ++n) {
            int o = (wc*64 + n*16 + (lane&15))*32 + ((lane>>4)*8);
            bh[n] = *(const bf16x8*)&Bsh[o];
            bl[n] = *(const bf16x8*)&Bsl[o];
        }
#pragma unroll
        for (int m = 0; m < 4; ++m)
#pragma unroll
            for (int n = 0; n < 4; ++n) {
                acc[m][n] = __builtin_amdgcn_mfma_f32_16x16x32_bf16(al[m], bh[n], acc[m][n], 0, 0, 0);
                acc[m][n] = __builtin_amdgcn_mfma_f32_16x16x32_bf16(ah[m], bl[n], acc[m][n], 0, 0, 0);
                acc[m][n] = __builtin_amdgcn_mfma_f32_16x16x32_bf16(ah[m], bh[n], acc[m][n], 0, 0, 0);
            }
        __syncthreads();
    }
    // epilogue: this wave's 64 cols = exactly one head
    const int headg = bx*2 + wc;                 // 0..31
    bf16* dh = (headg < 16) ? qhb : khb;
    bf16* dl = (headg < 16) ? qlb : klb;
    const int h = headg & 15;
    const int lr = lane & 15, lg4 = lane >> 4;
#pragma unroll
    for (int m = 0; m < 4; ++m)
#pragma unroll
        for (int r = 0; r < 4; ++r) {
            float ss = acc[m][0][r]*acc[m][0][r] + acc[m][1][r]*acc[m][1][r]
                     + acc[m][2][r]*acc[m][2][r] + acc[m][3][r]*acc[m][3][r];
#pragma unroll
            for (int off = 1; off < 16; off <<= 1) ss += __shfl_xor(ss, off, 64);
            float sc = 1.0f / fmaxf(sqrtf(ss), 1e-12f);
            int token = by*128 + wr*64 + m*16 + lg4*4 + r;
#pragma unroll
            for (int n = 0; n < 4; ++n) {
                int d = n*16 + lr;
                float qv = acc[m][n][r] * sc;
                bf16 hv = (bf16)qv;
                size_t idx = ((size_t)token*H_ + h)*64 + d;
                dh[idx] = hv;
                dl[idx] = (bf16)(qv - (float)hv);
            }
        }
}

// ---- plain GEMM (V|G) N=2048 + transposed-V / silu-G epilogue ----
__global__ __launch_bounds__(256) void gemm_vg_kernel(
    const bf16* __restrict__ A, const bf16* __restrict__ BT,
    bf16* __restrict__ vt, float* __restrict__ Gf) {
    const int K = E_;
    __shared__ __align__(16) bf16 As[128*32];
    __shared__ __align__(16) bf16 Bs[128*32];
    int bid = blockIdx.x;
    bid = (bid & 7) * 64 + (bid >> 3);           // XCD swizzle, 512 blocks
    const int bx = bid & 15, by = bid >> 4;
    const int tid = threadIdx.x, lane = tid & 63, wid = tid >> 6;
    const int wr = wid >> 1, wc = wid & 1;
    f32x4 acc[4][4];
#pragma unroll
    for (int m = 0; m < 4; ++m)
#pragma unroll
        for (int n = 0; n < 4; ++n) acc[m][n] = (f32x4)0.0f;
    const int tr = tid >> 2;
    const int tc = (tid & 3) * 8;
    for (int k0 = 0; k0 < K; k0 += 32) {
#pragma unroll
        for (int i = 0; i < 2; ++i) {
            gl_lds16(A  + (size_t)(by*128 + i*64 + tr)*K + k0 + tc, &As[(i*256 + wid*64)*8]);
            gl_lds16(BT + (size_t)(bx*128 + i*64 + tr)*K + k0 + tc, &Bs[(i*256 + wid*64)*8]);
        }
        __syncthreads();
        bf16x8 af[4], bfr[4];
#pragma unroll
        for (int m = 0; m < 4; ++m)
            af[m] = *(const bf16x8*)&As[(wr*64 + m*16 + (lane&15))*32 + ((lane>>4)*8)];
#pragma unroll
        for (int n = 0; n < 4; ++n)
            bfr[n] = *(const bf16x8*)&Bs[(wc*64 + n*16 + (lane&15))*32 + ((lane>>4)*8)];
#pragma unroll
        for (int m = 0; m < 4; ++m)
#pragma unroll
            for (int n = 0; n < 4; ++n)
                acc[m][n] = __builtin_amdgcn_mfma_f32_16x16x32_bf16(af[m], bfr[n], acc[m][n], 0, 0, 0);
        __syncthreads();
    }
    const int lr = lane & 15, lg4 = lane >> 4;
    const int colbase = bx*128 + wc*64;
    const int b = by >> 4;                       // 128-row tile lies in one batch
    if (colbase < 1024) {
        // V half: write vt[(b*H+head)*64 + d][t] (bf16, 4 tokens packed)
        const int head = colbase >> 6;
#pragma unroll
        for (int m = 0; m < 4; ++m) {
            int trow = by*128 + wr*64 + m*16 + lg4*4;
            int tloc = trow - b*T_;
#pragma unroll
            for (int n = 0; n < 4; ++n) {
                int d = n*16 + lr;
                bf16x4 pk;
                pk[0] = (bf16)acc[m][n][0]; pk[1] = (bf16)acc[m][n][1];
                pk[2] = (bf16)acc[m][n][2]; pk[3] = (bf16)acc[m][n][3];
                *(bf16x4*)(vt + ((size_t)((b*H_ + head)*64 + d))*T_ + tloc) = pk;
            }
        }
    } else {
        // G half: silu, write f32 [token][E]
#pragma unroll
        for (int m = 0; m < 4; ++m)
#pragma unroll
            for (int r = 0; r < 4; ++r) {
                int token = by*128 + wr*64 + m*16 + lg4*4 + r;
#pragma unroll
                for (int n = 0; n < 4; ++n) {
                    int colg = colbase - 1024 + n*16 + lr;
                    float g = acc[m][n][r];
                    Gf[(size_t)token*E_ + colg] = g / (1.0f + __expf(-g));
                }
            }
    }
}

// ---- output GEMM: out f32 = Yb bf16 @ WoT, 128x64 tile ----
__global__ __launch_bounds__(256) void gemm_out_kernel(
    const bf16* __restrict__ A, const bf16* __restrict__ BT, float* __restrict__ C) {
    const int K = E_, N = E_;
    __shared__ __align__(16) bf16 As[128*32];
    __shared__ __align__(16) bf16 Bs[64*32];
    int bid = blockIdx.x;
    bid = (bid & 7) * 64 + (bid >> 3);           // XCD swizzle, 512 blocks
    const int bx = bid & 15, by = bid >> 4;      // nbx = 1024/64 = 16
    const int tid = threadIdx.x, lane = tid & 63, wid = tid >> 6;
    const int wr = wid >> 1, wc = wid & 1;       // waves 64x32
    f32x4 acc[4][2];
#pragma unroll
    for (int m = 0; m < 4; ++m)
#pragma unroll
        for (int n = 0; n < 2; ++n) acc[m][n] = (f32x4)0.0f;
    const int tr = tid >> 2;
    const int tc = (tid & 3) * 8;
    for (int k0 = 0; k0 < K; k0 += 32) {
#pragma unroll
        for (int i = 0; i < 2; ++i)
            gl_lds16(A + (size_t)(by*128 + i*64 + tr)*K + k0 + tc, &As[(i*256 + wid*64)*8]);
        gl_lds16(BT + (size_t)(bx*64 + tid/4)*K + k0 + tc, &Bs[(wid*64)*8]);
        __syncthreads();
        bf16x8 af[4], bfr[2];
#pragma unroll
        for (int m = 0; m < 4; ++m)
            af[m] = *(const bf16x8*)&As[(wr*64 + m*16 + (lane&15))*32 + ((lane>>4)*8)];
#pragma unroll
        for (int n = 0; n < 2; ++n)
            bfr[n] = *(const bf16x8*)&Bs[(wc*32 + n*16 + (lane&15))*32 + ((lane>>4)*8)];
#pragma unroll
        for (int m = 0; m < 4; ++m)
#pragma unroll
            for (int n = 0; n < 2; ++n)
                acc[m][n] = __builtin_amdgcn_mfma_f32_16x16x32_bf16(af[m], bfr[n], acc[m][n], 0, 0, 0);
        __syncthreads();
    }
    const int crow = by*128 + wr*64;
    const int ccol = bx*64 + wc*32 + (lane & 15);
#pragma unroll
    for (int m = 0; m < 4; ++m)
#pragma unroll
        for (int r = 0; r < 4; ++r) {
            int row = crow + m*16 + (lane>>4)*4 + r;
#pragma unroll
            for (int n = 0; n < 2; ++n)
                C[(size_t)row*N + ccol + n*16] = acc[m][n][r];
        }
}

// ---- decay attention QBLK=128 + swizzled LDS + RMSNorm + gate -> Y bf16 ----
__global__ __launch_bounds__(256) void attn_kernel(
    const bf16* __restrict__ qh, const bf16* __restrict__ ql,
    const bf16* __restrict__ kh, const bf16* __restrict__ kl,
    const bf16* __restrict__ vt, const double* __restrict__ cl,
    const float* __restrict__ Gf, const float* __restrict__ rms_w,
    bf16* __restrict__ Y) {
    __shared__ __align__(16) bf16 Ksh[64*64];  // [key][d] swizzled
    __shared__ __align__(16) bf16 Ksl[64*64];
    __shared__ __align__(16) bf16 Vs[64*64];   // [d][key] swizzled
    __shared__ __align__(16) bf16 Ps[128*64];  // [qrow][key] swizzled
    const int rank = blockIdx.x >> 5, bh = blockIdx.x & 31;
    const int it = (T_/128 - 1) - rank;        // descending work order (LPT)
    const int b = bh >> 4, h = bh & 15;
    const int tid = threadIdx.x, lane = tid & 63, wid = tid >> 6;
    const int i0 = it * 128;
    const int lr = lane & 15, lg4 = lane >> 4;
    // Q fragments: wave owns rows i0 + wid*32 .. +32 (2 m-frags)
    bf16x8 qfh[2][2], qfl[2][2];
#pragma unroll
    for (int mm = 0; mm < 2; ++mm) {
        int qtok = i0 + wid*32 + mm*16 + lr;
        size_t qa = (size_t)(b*T_ + qtok)*E_ + h*64 + lg4*8;
        qfh[mm][0] = *(const bf16x8*)(qh + qa);
        qfh[mm][1] = *(const bf16x8*)(qh + qa + 32);
        qfl[mm][0] = *(const bf16x8*)(ql + qa);
        qfl[mm][1] = *(const bf16x8*)(ql + qa + 32);
    }
    const double* clrow = cl + (size_t)bh*T_;
    double cli[2][4];
#pragma unroll
    for (int mm = 0; mm < 2; ++mm)
#pragma unroll
        for (int r = 0; r < 4; ++r)
            cli[mm][r] = clrow[i0 + wid*32 + mm*16 + lg4*4 + r];
    f32x4 oacc[2][4];
#pragma unroll
    for (int mm = 0; mm < 2; ++mm)
#pragma unroll
        for (int n = 0; n < 4; ++n) oacc[mm][n] = (f32x4)0.0f;
    const int srow8 = lane >> 3;                 // 0..7 within 8-row group
    const int csrc  = (lane & 7) ^ srow8;        // pre-swizzled source chunk
    const int niter = 2*it + 2;
    for (int jt = 0; jt < niter; ++jt) {
        const int j0 = jt * 64;
#pragma unroll
        for (int i = 0; i < 2; ++i) {
            int krow = j0 + i*32 + wid*8 + srow8;
            int drow = i*32 + wid*8 + srow8;
            size_t gk = (size_t)(b*T_ + krow)*E_ + h*64 + csrc*8;
            gl_lds16(kh + gk, &Ksh[(i*32 + wid*8)*64]);
            gl_lds16(kl + gk, &Ksl[(i*32 + wid*8)*64]);
            gl_lds16(vt + (size_t)(bh*64 + drow)*T_ + j0 + csrc*8, &Vs[(i*32 + wid*8)*64]);
        }
        __syncthreads();
        // S = (qh+ql)(kh+kl)^T (3 products), decay+mask, write P (own rows)
#pragma unroll
        for (int n = 0; n < 4; ++n) {
            const int r = n*16 + lr;             // key row in tile
            const int sw = r & 7;
            const int ko = r*64;
            bf16x8 k_h0 = *(const bf16x8*)&Ksh[ko + ((lg4 ^ sw)*8)];
            bf16x8 k_h1 = *(const bf16x8*)&Ksh[ko + (((lg4+4) ^ sw)*8)];
            bf16x8 k_l0 = *(const bf16x8*)&Ksl[ko + ((lg4 ^ sw)*8)];
            bf16x8 k_l1 = *(const bf16x8*)&Ksl[ko + (((lg4+4) ^ sw)*8)];
            const int j = j0 + r;                // global key index
            const double clj = clrow[j];
#pragma unroll
            for (int mm = 0; mm < 2; ++mm) {
                f32x4 s = (f32x4)0.0f;
                s = __builtin_amdgcn_mfma_f32_16x16x32_bf16(qfl[mm][0], k_h0, s, 0, 0, 0);
                s = __builtin_amdgcn_mfma_f32_16x16x32_bf16(qfl[mm][1], k_h1, s, 0, 0, 0);
                s = __builtin_amdgcn_mfma_f32_16x16x32_bf16(qfh[mm][0], k_l0, s, 0, 0, 0);
                s = __builtin_amdgcn_mfma_f32_16x16x32_bf16(qfh[mm][1], k_l1, s, 0, 0, 0);
                s = __builtin_amdgcn_mfma_f32_16x16x32_bf16(qfh[mm][0], k_h0, s, 0, 0, 0);
                s = __builtin_amdgcn_mfma_f32_16x16x32_bf16(qfh[mm][1], k_h1, s, 0, 0, 0);
                const int prbase = wid*32 + mm*16 + lg4*4;
#pragma unroll
                for (int r4 = 0; r4 < 4; ++r4) {
                    const int pr = prbase + r4;
                    const int qrow = i0 + pr;
                    float val = (j <= qrow)
                        ? s[r4] * __expf((float)(cli[mm][r4] - clj)) : 0.0f;
                    const int cw = n*2 + (lr >> 3);
                    Ps[pr*64 + ((cw ^ (pr & 7))*8) + (lane & 7)] = (bf16)val;
                }
            }
        }
        // O += P V  (same-wave P round trip; lgkmcnt ordering suffices)
#pragma unroll
        for (int kk = 0; kk < 2; ++kk) {
            const int js = kk*4 + lg4;
            bf16x8 pf[2];
#pragma unroll
            for (int mm = 0; mm < 2; ++mm) {
                const int rp = wid*32 + mm*16 + lr;
                pf[mm] = *(const bf16x8*)&Ps[rp*64 + ((js ^ (rp & 7))*8)];
            }
#pragma unroll
            for (int n = 0; n < 4; ++n) {
                const int rv = n*16 + lr;
                bf16x8 vf = *(const bf16x8*)&Vs[rv*64 + ((js ^ (rv & 7))*8)];
                oacc[0][n] = __builtin_amdgcn_mfma_f32_16x16x32_bf16(pf[0], vf, oacc[0][n], 0, 0, 0);
                oacc[1][n] = __builtin_amdgcn_mfma_f32_16x16x32_bf16(pf[1], vf, oacc[1][n], 0, 0, 0);
            }
        }
        __syncthreads();
    }
    // epilogue: RMSNorm over d=64, * rms_w, * pre-silu'd gate -> bf16 Y
#pragma unroll
    for (int mm = 0; mm < 2; ++mm)
#pragma unroll
        for (int r = 0; r < 4; ++r) {
            float ss = oacc[mm][0][r]*oacc[mm][0][r] + oacc[mm][1][r]*oacc[mm][1][r]
                     + oacc[mm][2][r]*oacc[mm][2][r] + oacc[mm][3][r]*oacc[mm][3][r];
#pragma unroll
            for (int off = 1; off < 16; off <<= 1) ss += __shfl_xor(ss, off, 64);
            const float scale = rsqrtf(ss * (1.0f/64.0f) + 1e-6f);
            const int gtok = b*T_ + i0 + wid*32 + mm*16 + lg4*4 + r;
#pragma unroll
            for (int n = 0; n < 4; ++n) {
                const int d = n*16 + lr;
                float o = oacc[mm][n][r] * scale * rms_w[d];
                float gate = Gf[(size_t)gtok*E_ + h*64 + d];
                Y[(size_t)gtok*E_ + h*64 + d] = (bf16)(o * gate);
            }
        }
}

extern "C" void kernel_launch(void* const* d_in, const int* in_sizes, int n_in,
                              void* d_out, int out_size, void* d_ws, size_t ws_size,
                              hipStream_t stream) {
    const float* x       = (const float*)d_in[0];
    const float* Wq      = (const float*)d_in[1];
    const float* Wk      = (const float*)d_in[2];
    const float* Wv      = (const float*)d_in[3];
    const float* Wa      = (const float*)d_in[4];
    const float* Wg      = (const float*)d_in[5];
    const float* Wo      = (const float*)d_in[6];
    const float* A_log   = (const float*)d_in[7];
    const float* dt_bias = (const float*)d_in[8];
    const float* rms_w   = (const float*)d_in[9];
    float* out = (float*)d_out;

    char* w = (char*)d_ws;
    size_t off = 0;
    auto alloc = [&](size_t bytes) {
        void* p = w + off; off += (bytes + 255) & ~(size_t)255; return p;
    };
    bf16*   xh   = (bf16*)  alloc((size_t)MTOK*E_*2);
    bf16*   xl   = (bf16*)  alloc((size_t)MTOK*E_*2);
    bf16*   WTqh = (bf16*)  alloc((size_t)2048*E_*2);
    bf16*   WTql = (bf16*)  alloc((size_t)2048*E_*2);
    bf16*   WTvg = (bf16*)  alloc((size_t)2048*E_*2);
    bf16*   WTo  = (bf16*)  alloc((size_t)E_*E_*2);
    bf16*   qhb  = (bf16*)  alloc((size_t)MTOK*E_*2);
    bf16*   qlb  = (bf16*)  alloc((size_t)MTOK*E_*2);
    bf16*   khb  = (bf16*)  alloc((size_t)MTOK*E_*2);
    bf16*   klb  = (bf16*)  alloc((size_t)MTOK*E_*2);
    bf16*   vt   = (bf16*)  alloc((size_t)MTOK*E_*2);
    float*  Gf   = (float*) alloc((size_t)MTOK*E_*4);
    float*  lg   = (float*) alloc((size_t)B_*H_*T_*4);
    double* cl   = (double*)alloc((size_t)B_*H_*T_*8);
    bf16*   Yb   = (bf16*)  alloc((size_t)MTOK*E_*2);

    dim3 tb(32, 8);

    hipLaunchKernelGGL(f2b_split_kernel, dim3(MTOK*E_/1024), dim3(256), 0, stream, x, xh, xl, MTOK*E_);
    hipLaunchKernelGGL(dt_kernel,  dim3(MTOK), dim3(256), 0, stream, x, Wa, A_log, dt_bias, lg);
    hipLaunchKernelGGL(scan_kernel, dim3(B_*H_), dim3(256), 0, stream, lg, cl);

    // weight prep
    hipLaunchKernelGGL(tconv_split_kernel, dim3(1024), tb, 0, stream, Wq, WTqh, WTql, E_, E_);
    hipLaunchKernelGGL(tconv_split_kernel, dim3(1024), tb, 0, stream, Wk,
                       WTqh + (size_t)1024*1024, WTql + (size_t)1024*1024, E_, E_);
    hipLaunchKernelGGL(tconv_kernel, dim3(1024), tb, 0, stream, Wv, WTvg, E_, E_);
    hipLaunchKernelGGL(tconv_kernel, dim3(1024), tb, 0, stream, Wg, WTvg + (size_t)1024*1024, E_, E_);
    hipLaunchKernelGGL(tconv_kernel, dim3(1024), tb, 0, stream, Wo, WTo, E_, E_);

    // fused projections
    hipLaunchKernelGGL(gemm_qk_kernel, dim3(512), dim3(256), 0, stream,
                       xh, xl, WTqh, WTql, qhb, qlb, khb, klb);
    hipLaunchKernelGGL(gemm_vg_kernel, dim3(512), dim3(256), 0, stream,
                       xh, WTvg, vt, Gf);

    // attention + RMSNorm + gate
    hipLaunchKernelGGL(attn_kernel, dim3(512), dim3(256), 0, stream,
                       qhb, qlb, khb, klb, vt, cl, Gf, rms_w, Yb);

    // output projection
    hipLaunchKernelGGL(gemm_out_kernel, dim3(512), dim3(256), 0, stream, Yb, WTo, out);
}

// Round 5
// 253.740 us; speedup vs baseline: 2.0190x; 1.4128x over previous
//
#include <hip/hip_runtime.h>
#include <hip/hip_bf16.h>
#include <math.h>

#define B_ 2
#define T_ 2048
#define E_ 1024
#define H_ 16
#define D_ 64
#define MTOK (B_*T_)   // 4096

typedef __bf16 bf16;
typedef __bf16 bf16x8 __attribute__((ext_vector_type(8)));
typedef __bf16 bf16x4 __attribute__((ext_vector_type(4)));
typedef float  f32x4  __attribute__((ext_vector_type(4)));

__device__ __forceinline__ void gl_lds16(const void* g, void* l) {
    __builtin_amdgcn_global_load_lds(
        (const __attribute__((address_space(1))) void*)g,
        (__attribute__((address_space(3))) void*)l, 16, 0, 0);
}

// ---------------- f32 -> bf16 hi/lo split elementwise (16B stores) ----------------
__global__ __launch_bounds__(256) void f2b_split_kernel(const float* __restrict__ s,
                                                        bf16* __restrict__ hi,
                                                        bf16* __restrict__ lo, int n) {
    int i = (blockIdx.x * 256 + threadIdx.x) * 8;
    if (i + 7 < n) {
        float4 a = *(const float4*)(s + i);
        float4 b = *(const float4*)(s + i + 4);
        float va[8] = {a.x, a.y, a.z, a.w, b.x, b.y, b.z, b.w};
        bf16x8 hv, lv;
#pragma unroll
        for (int j = 0; j < 8; ++j) {
            bf16 h = (bf16)va[j];
            hv[j] = h;
            lv[j] = (bf16)(va[j] - (float)h);
        }
        *(bf16x8*)(hi + i) = hv;
        *(bf16x8*)(lo + i) = lv;
    }
}

// ---------------- W [K,N] f32 -> W^T [N,K] bf16 (plain) ----------------
__global__ void tconv_kernel(const float* __restrict__ src, bf16* __restrict__ dst,
                             int rows, int cols) {
    __shared__ float t[32][33];
    int nbx = cols >> 5;
    int bx = blockIdx.x % nbx, by = blockIdx.x / nbx;
    int tx = threadIdx.x, ty = threadIdx.y;
#pragma unroll
    for (int i = ty; i < 32; i += 8)
        t[i][tx] = src[(size_t)(by*32 + i)*cols + bx*32 + tx];
    __syncthreads();
#pragma unroll
    for (int i = ty; i < 32; i += 8)
        dst[(size_t)(bx*32 + i)*rows + by*32 + tx] = (bf16)t[tx][i];
}

// ---------------- W [K,N] f32 -> W^T [N,K] bf16 hi/lo split ----------------
__global__ void tconv_split_kernel(const float* __restrict__ src,
                                   bf16* __restrict__ dh, bf16* __restrict__ dl,
                                   int rows, int cols) {
    __shared__ float t[32][33];
    int nbx = cols >> 5;
    int bx = blockIdx.x % nbx, by = blockIdx.x / nbx;
    int tx = threadIdx.x, ty = threadIdx.y;
#pragma unroll
    for (int i = ty; i < 32; i += 8)
        t[i][tx] = src[(size_t)(by*32 + i)*cols + bx*32 + tx];
    __syncthreads();
#pragma unroll
    for (int i = ty; i < 32; i += 8) {
        float v = t[tx][i];
        bf16 h = (bf16)v;
        size_t idx = (size_t)(bx*32 + i)*rows + by*32 + tx;
        dh[idx] = h;
        dl[idx] = (bf16)(v - (float)h);
    }
}

// ---------------- Wa [1024][16] f32 -> WaT [16][1024] f32 ----------------
__global__ __launch_bounds__(256) void waT_kernel(const float* __restrict__ Wa,
                                                  float* __restrict__ WaT) {
    int idx = blockIdx.x * 256 + threadIdx.x;    // grid 64 -> 16384
    int h = idx >> 10, k = idx & 1023;
    WaT[idx] = Wa[k*H_ + h];
}

// ---------------- dt -> log(alpha + 1e-8): LDS-staged x, 16 tokens/block ----------------
__global__ __launch_bounds__(256) void dt_kernel(const float* __restrict__ x,
                                                 const float* __restrict__ WaT,
                                                 const float* __restrict__ A_log,
                                                 const float* __restrict__ dt_bias,
                                                 float* __restrict__ lg) {
    __shared__ float xs[16][1032];               // pad 8 -> token banks {0,8,16,24}
    const int tb = blockIdx.x * 16;              // grid 256
    const int tid = threadIdx.x;
#pragma unroll
    for (int v = tid; v < 4096; v += 256) {
        int row = v >> 8, c4 = (v & 255) * 4;
        float4 val = *(const float4*)(x + (size_t)(tb + row)*E_ + c4);
        xs[row][c4+0] = val.x; xs[row][c4+1] = val.y;
        xs[row][c4+2] = val.z; xs[row][c4+3] = val.w;
    }
    __syncthreads();
    const int i = tid >> 4, h = tid & 15;
    const float* wrow = WaT + (size_t)h*1024;
    float acc = 0.f;
#pragma unroll 8
    for (int k = 0; k < 1024; k += 4) {
        float4 xv = *(const float4*)&xs[i][k];
        float4 wv = *(const float4*)(wrow + k);
        acc += xv.x*wv.x + xv.y*wv.y + xv.z*wv.z + xv.w*wv.w;
    }
    float z   = acc + dt_bias[h];
    float dtv = (z > 20.f) ? z : log1pf(expf(z));
    float la  = -expf(A_log[h]) * dtv;
    float l   = logf(expf(la) + 1e-8f);
    int n = tb + i;
    int b = n / T_, t = n % T_;
    lg[(size_t)(b*H_ + h)*T_ + t] = l;
}

// ---------------- f64 inclusive scan of lg rows -> cl ----------------
__global__ __launch_bounds__(256) void scan_kernel(const float* __restrict__ lg,
                                                   double* __restrict__ cl) {
    int row = blockIdx.x, tid = threadIdx.x;
    __shared__ double ls[256];
    const float* p = lg + (size_t)row*T_ + tid*8;
    double loc[8], s = 0.0;
#pragma unroll
    for (int j = 0; j < 8; ++j) { s += (double)p[j]; loc[j] = s; }
    ls[tid] = s;
    __syncthreads();
    for (int off = 1; off < 256; off <<= 1) {
        double add = (tid >= off) ? ls[tid - off] : 0.0;
        __syncthreads();
        ls[tid] += add;
        __syncthreads();
    }
    double prefix = ls[tid] - s;
    double* o = cl + (size_t)row*T_ + tid*8;
#pragma unroll
    for (int j = 0; j < 8; ++j) o[j] = prefix + loc[j];
}

// ---- fused split GEMM (Q|K) N=2048 + L2-norm + hi/lo split epilogue ----
__global__ __launch_bounds__(256) void gemm_qk_kernel(
    const bf16* __restrict__ Ah, const bf16* __restrict__ Al,
    const bf16* __restrict__ Bh, const bf16* __restrict__ Bl,
    bf16* __restrict__ qhb, bf16* __restrict__ qlb,
    bf16* __restrict__ khb, bf16* __restrict__ klb) {
    const int K = E_;
    __shared__ __align__(16) bf16 Ash[128*32];
    __shared__ __align__(16) bf16 Asl[128*32];
    __shared__ __align__(16) bf16 Bsh[128*32];
    __shared__ __align__(16) bf16 Bsl[128*32];
    int bid = blockIdx.x;
    bid = (bid & 7) * 64 + (bid >> 3);           // XCD swizzle, 512 blocks
    const int bx = bid & 15, by = bid >> 4;      // nbx = 2048/128 = 16
    const int tid = threadIdx.x, lane = tid & 63, wid = tid >> 6;
    const int wr = wid >> 1, wc = wid & 1;
    f32x4 acc[4][4];
#pragma unroll
    for (int m = 0; m < 4; ++m)
#pragma unroll
        for (int n = 0; n < 4; ++n) acc[m][n] = (f32x4)0.0f;
    const int tr = tid >> 2;
    const int tc = (tid & 3) * 8;
    for (int k0 = 0; k0 < K; k0 += 32) {
#pragma unroll
        for (int i = 0; i < 2; ++i) {
            size_t ga = (size_t)(by*128 + i*64 + tr)*K + k0 + tc;
            size_t gb = (size_t)(bx*128 + i*64 + tr)*K + k0 + tc;
            gl_lds16(Ah + ga, &Ash[(i*256 + wid*64)*8]);
            gl_lds16(Al + ga, &Asl[(i*256 + wid*64)*8]);
            gl_lds16(Bh + gb, &Bsh[(i*256 + wid*64)*8]);
            gl_lds16(Bl + gb, &Bsl[(i*256 + wid*64)*8]);
        }
        __syncthreads();
        bf16x8 ah[4], al[4], bh[4], bl[4];
#pragma unroll
        for (int m = 0; m < 4; ++m) {
            int o = (wr*64 + m*16 + (lane&15))*32 + ((lane>>4)*8);
            ah[m] = *(const bf16x8*)&Ash[o];
            al[m] = *(const bf16x8*)&Asl[o];
        }
#pragma unroll
        for (int n = 0; n < 4; ++n) {
            int o = (wc*64 + n*16 + (lane&15))*32 + ((lane>>4)*8);
            bh[n] = *(const bf16x8*)&Bsh[o];
            bl[n] = *(const bf16x8*)&Bsl[o];
        }
#pragma unroll
        for (int m = 0; m < 4; ++m)
#pragma unroll
            for (int n = 0; n < 4; ++n) {
                acc[m][n] = __builtin_amdgcn_mfma_f32_16x16x32_bf16(al[m], bh[n], acc[m][n], 0, 0, 0);
                acc[m][n] = __builtin_amdgcn_mfma_f32_16x16x32_bf16(ah[m], bl[n], acc[m][n], 0, 0, 0);
                acc[m][n] = __builtin_amdgcn_mfma_f32_16x16x32_bf16(ah[m], bh[n], acc[m][n], 0, 0, 0);
            }
        __syncthreads();
    }
    // epilogue: this wave's 64 cols = exactly one head
    const int headg = bx*2 + wc;                 // 0..31
    bf16* dh = (headg < 16) ? qhb : khb;
    bf16* dl = (headg < 16) ? qlb : klb;
    const int h = headg & 15;
    const int lr = lane & 15, lg4 = lane >> 4;
#pragma unroll
    for (int m = 0; m < 4; ++m)
#pragma unroll
        for (int r = 0; r < 4; ++r) {
            float ss = acc[m][0][r]*acc[m][0][r] + acc[m][1][r]*acc[m][1][r]
                     + acc[m][2][r]*acc[m][2][r] + acc[m][3][r]*acc[m][3][r];
#pragma unroll
            for (int off = 1; off < 16; off <<= 1) ss += __shfl_xor(ss, off, 64);
            float sc = 1.0f / fmaxf(sqrtf(ss), 1e-12f);
            int token = by*128 + wr*64 + m*16 + lg4*4 + r;
#pragma unroll
            for (int n = 0; n < 4; ++n) {
                int d = n*16 + lr;
                float qv = acc[m][n][r] * sc;
                bf16 hv = (bf16)qv;
                size_t idx = ((size_t)token*H_ + h)*64 + d;
                dh[idx] = hv;
                dl[idx] = (bf16)(qv - (float)hv);
            }
        }
}

// ---- plain GEMM (V|G) N=2048 + transposed-V / silu-G epilogue ----
__global__ __launch_bounds__(256) void gemm_vg_kernel(
    const bf16* __restrict__ A, const bf16* __restrict__ BT,
    bf16* __restrict__ vt, float* __restrict__ Gf) {
    const int K = E_;
    __shared__ __align__(16) bf16 As[128*32];
    __shared__ __align__(16) bf16 Bs[128*32];
    int bid = blockIdx.x;
    bid = (bid & 7) * 64 + (bid >> 3);           // XCD swizzle, 512 blocks
    const int bx = bid & 15, by = bid >> 4;
    const int tid = threadIdx.x, lane = tid & 63, wid = tid >> 6;
    const int wr = wid >> 1, wc = wid & 1;
    f32x4 acc[4][4];
#pragma unroll
    for (int m = 0; m < 4; ++m)
#pragma unroll
        for (int n = 0; n < 4; ++n) acc[m][n] = (f32x4)0.0f;
    const int tr = tid >> 2;
    const int tc = (tid & 3) * 8;
    for (int k0 = 0; k0 < K; k0 += 32) {
#pragma unroll
        for (int i = 0; i < 2; ++i) {
            gl_lds16(A  + (size_t)(by*128 + i*64 + tr)*K + k0 + tc, &As[(i*256 + wid*64)*8]);
            gl_lds16(BT + (size_t)(bx*128 + i*64 + tr)*K + k0 + tc, &Bs[(i*256 + wid*64)*8]);
        }
        __syncthreads();
        bf16x8 af[4], bfr[4];
#pragma unroll
        for (int m = 0; m < 4; ++m)
            af[m] = *(const bf16x8*)&As[(wr*64 + m*16 + (lane&15))*32 + ((lane>>4)*8)];
#pragma unroll
        for (int n = 0; n < 4; ++n)
            bfr[n] = *(const bf16x8*)&Bs[(wc*64 + n*16 + (lane&15))*32 + ((lane>>4)*8)];
#pragma unroll
        for (int m = 0; m < 4; ++m)
#pragma unroll
            for (int n = 0; n < 4; ++n)
                acc[m][n] = __builtin_amdgcn_mfma_f32_16x16x32_bf16(af[m], bfr[n], acc[m][n], 0, 0, 0);
        __syncthreads();
    }
    const int lr = lane & 15, lg4 = lane >> 4;
    const int colbase = bx*128 + wc*64;
    const int b = by >> 4;                       // 128-row tile lies in one batch
    if (colbase < 1024) {
        // V half: write vt[(b*H+head)*64 + d][t] (bf16, 4 tokens packed)
        const int head = colbase >> 6;
#pragma unroll
        for (int m = 0; m < 4; ++m) {
            int trow = by*128 + wr*64 + m*16 + lg4*4;
            int tloc = trow - b*T_;
#pragma unroll
            for (int n = 0; n < 4; ++n) {
                int d = n*16 + lr;
                bf16x4 pk;
                pk[0] = (bf16)acc[m][n][0]; pk[1] = (bf16)acc[m][n][1];
                pk[2] = (bf16)acc[m][n][2]; pk[3] = (bf16)acc[m][n][3];
                *(bf16x4*)(vt + ((size_t)((b*H_ + head)*64 + d))*T_ + tloc) = pk;
            }
        }
    } else {
        // G half: silu, write f32 [token][E]
#pragma unroll
        for (int m = 0; m < 4; ++m)
#pragma unroll
            for (int r = 0; r < 4; ++r) {
                int token = by*128 + wr*64 + m*16 + lg4*4 + r;
#pragma unroll
                for (int n = 0; n < 4; ++n) {
                    int colg = colbase - 1024 + n*16 + lr;
                    float g = acc[m][n][r];
                    Gf[(size_t)token*E_ + colg] = g / (1.0f + __expf(-g));
                }
            }
    }
}

// ---- output GEMM: out f32 = Yb bf16 @ WoT, 128x64 tile ----
__global__ __launch_bounds__(256) void gemm_out_kernel(
    const bf16* __restrict__ A, const bf16* __restrict__ BT, float* __restrict__ C) {
    const int K = E_, N = E_;
    __shared__ __align__(16) bf16 As[128*32];
    __shared__ __align__(16) bf16 Bs[64*32];
    int bid = blockIdx.x;
    bid = (bid & 7) * 64 + (bid >> 3);           // XCD swizzle, 512 blocks
    const int bx = bid & 15, by = bid >> 4;      // nbx = 1024/64 = 16
    const int tid = threadIdx.x, lane = tid & 63, wid = tid >> 6;
    const int wr = wid >> 1, wc = wid & 1;       // waves 64x32
    f32x4 acc[4][2];
#pragma unroll
    for (int m = 0; m < 4; ++m)
#pragma unroll
        for (int n = 0; n < 2; ++n) acc[m][n] = (f32x4)0.0f;
    const int tr = tid >> 2;
    const int tc = (tid & 3) * 8;
    for (int k0 = 0; k0 < K; k0 += 32) {
#pragma unroll
        for (int i = 0; i < 2; ++i)
            gl_lds16(A + (size_t)(by*128 + i*64 + tr)*K + k0 + tc, &As[(i*256 + wid*64)*8]);
        gl_lds16(BT + (size_t)(bx*64 + tid/4)*K + k0 + tc, &Bs[(wid*64)*8]);
        __syncthreads();
        bf16x8 af[4], bfr[2];
#pragma unroll
        for (int m = 0; m < 4; ++m)
            af[m] = *(const bf16x8*)&As[(wr*64 + m*16 + (lane&15))*32 + ((lane>>4)*8)];
#pragma unroll
        for (int n = 0; n < 2; ++n)
            bfr[n] = *(const bf16x8*)&Bs[(wc*32 + n*16 + (lane&15))*32 + ((lane>>4)*8)];
#pragma unroll
        for (int m = 0; m < 4; ++m)
#pragma unroll
            for (int n = 0; n < 2; ++n)
                acc[m][n] = __builtin_amdgcn_mfma_f32_16x16x32_bf16(af[m], bfr[n], acc[m][n], 0, 0, 0);
        __syncthreads();
    }
    const int crow = by*128 + wr*64;
    const int ccol = bx*64 + wc*32 + (lane & 15);
#pragma unroll
    for (int m = 0; m < 4; ++m)
#pragma unroll
        for (int r = 0; r < 4; ++r) {
            int row = crow + m*16 + (lane>>4)*4 + r;
#pragma unroll
            for (int n = 0; n < 2; ++n)
                C[(size_t)row*N + ccol + n*16] = acc[m][n][r];
        }
}

// ---- decay attention QBLK=128 + swizzled LDS + RMSNorm + gate -> Y bf16 ----
__global__ __launch_bounds__(256) void attn_kernel(
    const bf16* __restrict__ qh, const bf16* __restrict__ ql,
    const bf16* __restrict__ kh, const bf16* __restrict__ kl,
    const bf16* __restrict__ vt, const double* __restrict__ cl,
    const float* __restrict__ Gf, const float* __restrict__ rms_w,
    bf16* __restrict__ Y) {
    __shared__ __align__(16) bf16 Ksh[64*64];  // [key][d] swizzled
    __shared__ __align__(16) bf16 Ksl[64*64];
    __shared__ __align__(16) bf16 Vs[64*64];   // [d][key] swizzled
    __shared__ __align__(16) bf16 Ps[128*64];  // [qrow][key] swizzled
    const int rank = blockIdx.x >> 5, bh = blockIdx.x & 31;
    const int it = (T_/128 - 1) - rank;        // descending work order (LPT)
    const int b = bh >> 4, h = bh & 15;
    const int tid = threadIdx.x, lane = tid & 63, wid = tid >> 6;
    const int i0 = it * 128;
    const int lr = lane & 15, lg4 = lane >> 4;
    // Q fragments: wave owns rows i0 + wid*32 .. +32 (2 m-frags)
    bf16x8 qfh[2][2], qfl[2][2];
#pragma unroll
    for (int mm = 0; mm < 2; ++mm) {
        int qtok = i0 + wid*32 + mm*16 + lr;
        size_t qa = (size_t)(b*T_ + qtok)*E_ + h*64 + lg4*8;
        qfh[mm][0] = *(const bf16x8*)(qh + qa);
        qfh[mm][1] = *(const bf16x8*)(qh + qa + 32);
        qfl[mm][0] = *(const bf16x8*)(ql + qa);
        qfl[mm][1] = *(const bf16x8*)(ql + qa + 32);
    }
    const double* clrow = cl + (size_t)bh*T_;
    double cli[2][4];
#pragma unroll
    for (int mm = 0; mm < 2; ++mm)
#pragma unroll
        for (int r = 0; r < 4; ++r)
            cli[mm][r] = clrow[i0 + wid*32 + mm*16 + lg4*4 + r];
    f32x4 oacc[2][4];
#pragma unroll
    for (int mm = 0; mm < 2; ++mm)
#pragma unroll
        for (int n = 0; n < 4; ++n) oacc[mm][n] = (f32x4)0.0f;
    const int srow8 = lane >> 3;                 // 0..7 within 8-row group
    const int csrc  = (lane & 7) ^ srow8;        // pre-swizzled source chunk
    const int niter = 2*it + 2;
    for (int jt = 0; jt < niter; ++jt) {
        const int j0 = jt * 64;
#pragma unroll
        for (int i = 0; i < 2; ++i) {
            int krow = j0 + i*32 + wid*8 + srow8;
            int drow = i*32 + wid*8 + srow8;
            size_t gk = (size_t)(b*T_ + krow)*E_ + h*64 + csrc*8;
            gl_lds16(kh + gk, &Ksh[(i*32 + wid*8)*64]);
            gl_lds16(kl + gk, &Ksl[(i*32 + wid*8)*64]);
            gl_lds16(vt + (size_t)(bh*64 + drow)*T_ + j0 + csrc*8, &Vs[(i*32 + wid*8)*64]);
        }
        __syncthreads();
        // S = (qh+ql)(kh+kl)^T (3 products), decay+mask, write P (own rows)
#pragma unroll
        for (int n = 0; n < 4; ++n) {
            const int r = n*16 + lr;             // key row in tile
            const int sw = r & 7;
            const int ko = r*64;
            bf16x8 k_h0 = *(const bf16x8*)&Ksh[ko + ((lg4 ^ sw)*8)];
            bf16x8 k_h1 = *(const bf16x8*)&Ksh[ko + (((lg4+4) ^ sw)*8)];
            bf16x8 k_l0 = *(const bf16x8*)&Ksl[ko + ((lg4 ^ sw)*8)];
            bf16x8 k_l1 = *(const bf16x8*)&Ksl[ko + (((lg4+4) ^ sw)*8)];
            const int j = j0 + r;                // global key index
            const double clj = clrow[j];
#pragma unroll
            for (int mm = 0; mm < 2; ++mm) {
                f32x4 s = (f32x4)0.0f;
                s = __builtin_amdgcn_mfma_f32_16x16x32_bf16(qfl[mm][0], k_h0, s, 0, 0, 0);
                s = __builtin_amdgcn_mfma_f32_16x16x32_bf16(qfl[mm][1], k_h1, s, 0, 0, 0);
                s = __builtin_amdgcn_mfma_f32_16x16x32_bf16(qfh[mm][0], k_l0, s, 0, 0, 0);
                s = __builtin_amdgcn_mfma_f32_16x16x32_bf16(qfh[mm][1], k_l1, s, 0, 0, 0);
                s = __builtin_amdgcn_mfma_f32_16x16x32_bf16(qfh[mm][0], k_h0, s, 0, 0, 0);
                s = __builtin_amdgcn_mfma_f32_16x16x32_bf16(qfh[mm][1], k_h1, s, 0, 0, 0);
                const int prbase = wid*32 + mm*16 + lg4*4;
#pragma unroll
                for (int r4 = 0; r4 < 4; ++r4) {
                    const int pr = prbase + r4;
                    const int qrow = i0 + pr;
                    float val = (j <= qrow)
                        ? s[r4] * __expf((float)(cli[mm][r4] - clj)) : 0.0f;
                    const int cw = n*2 + (lr >> 3);
                    Ps[pr*64 + ((cw ^ (pr & 7))*8) + (lane & 7)] = (bf16)val;
                }
            }
        }
        // O += P V  (same-wave P round trip; lgkmcnt ordering suffices)
#pragma unroll
        for (int kk = 0; kk < 2; ++kk) {
            const int js = kk*4 + lg4;
            bf16x8 pf[2];
#pragma unroll
            for (int mm = 0; mm < 2; ++mm) {
                const int rp = wid*32 + mm*16 + lr;
                pf[mm] = *(const bf16x8*)&Ps[rp*64 + ((js ^ (rp & 7))*8)];
            }
#pragma unroll
            for (int n = 0; n < 4; ++n) {
                const int rv = n*16 + lr;
                bf16x8 vf = *(const bf16x8*)&Vs[rv*64 + ((js ^ (rv & 7))*8)];
                oacc[0][n] = __builtin_amdgcn_mfma_f32_16x16x32_bf16(pf[0], vf, oacc[0][n], 0, 0, 0);
                oacc[1][n] = __builtin_amdgcn_mfma_f32_16x16x32_bf16(pf[1], vf, oacc[1][n], 0, 0, 0);
            }
        }
        __syncthreads();
    }
    // epilogue: RMSNorm over d=64, * rms_w, * pre-silu'd gate -> bf16 Y
#pragma unroll
    for (int mm = 0; mm < 2; ++mm)
#pragma unroll
        for (int r = 0; r < 4; ++r) {
            float ss = oacc[mm][0][r]*oacc[mm][0][r] + oacc[mm][1][r]*oacc[mm][1][r]
                     + oacc[mm][2][r]*oacc[mm][2][r] + oacc[mm][3][r]*oacc[mm][3][r];
#pragma unroll
            for (int off = 1; off < 16; off <<= 1) ss += __shfl_xor(ss, off, 64);
            const float scale = rsqrtf(ss * (1.0f/64.0f) + 1e-6f);
            const int gtok = b*T_ + i0 + wid*32 + mm*16 + lg4*4 + r;
#pragma unroll
            for (int n = 0; n < 4; ++n) {
                const int d = n*16 + lr;
                float o = oacc[mm][n][r] * scale * rms_w[d];
                float gate = Gf[(size_t)gtok*E_ + h*64 + d];
                Y[(size_t)gtok*E_ + h*64 + d] = (bf16)(o * gate);
            }
        }
}

extern "C" void kernel_launch(void* const* d_in, const int* in_sizes, int n_in,
                              void* d_out, int out_size, void* d_ws, size_t ws_size,
                              hipStream_t stream) {
    const float* x       = (const float*)d_in[0];
    const float* Wq      = (const float*)d_in[1];
    const float* Wk      = (const float*)d_in[2];
    const float* Wv      = (const float*)d_in[3];
    const float* Wa      = (const float*)d_in[4];
    const float* Wg      = (const float*)d_in[5];
    const float* Wo      = (const float*)d_in[6];
    const float* A_log   = (const float*)d_in[7];
    const float* dt_bias = (const float*)d_in[8];
    const float* rms_w   = (const float*)d_in[9];
    float* out = (float*)d_out;

    char* w = (char*)d_ws;
    size_t off = 0;
    auto alloc = [&](size_t bytes) {
        void* p = w + off; off += (bytes + 255) & ~(size_t)255; return p;
    };
    bf16*   xh   = (bf16*)  alloc((size_t)MTOK*E_*2);
    bf16*   xl   = (bf16*)  alloc((size_t)MTOK*E_*2);
    bf16*   WTqh = (bf16*)  alloc((size_t)2048*E_*2);
    bf16*   WTql = (bf16*)  alloc((size_t)2048*E_*2);
    bf16*   WTvg = (bf16*)  alloc((size_t)2048*E_*2);
    bf16*   WTo  = (bf16*)  alloc((size_t)E_*E_*2);
    bf16*   qhb  = (bf16*)  alloc((size_t)MTOK*E_*2);
    bf16*   qlb  = (bf16*)  alloc((size_t)MTOK*E_*2);
    bf16*   khb  = (bf16*)  alloc((size_t)MTOK*E_*2);
    bf16*   klb  = (bf16*)  alloc((size_t)MTOK*E_*2);
    bf16*   vt   = (bf16*)  alloc((size_t)MTOK*E_*2);
    float*  Gf   = (float*) alloc((size_t)MTOK*E_*4);
    float*  lg   = (float*) alloc((size_t)B_*H_*T_*4);
    double* cl   = (double*)alloc((size_t)B_*H_*T_*8);
    bf16*   Yb   = (bf16*)  alloc((size_t)MTOK*E_*2);
    float*  WaT  = (float*) alloc((size_t)H_*E_*4);

    dim3 tb(32, 8);

    hipLaunchKernelGGL(f2b_split_kernel, dim3(MTOK*E_/2048), dim3(256), 0, stream, x, xh, xl, MTOK*E_);
    hipLaunchKernelGGL(waT_kernel, dim3(64), dim3(256), 0, stream, Wa, WaT);
    hipLaunchKernelGGL(dt_kernel,  dim3(256), dim3(256), 0, stream, x, WaT, A_log, dt_bias, lg);
    hipLaunchKernelGGL(scan_kernel, dim3(B_*H_), dim3(256), 0, stream, lg, cl);

    // weight prep
    hipLaunchKernelGGL(tconv_split_kernel, dim3(1024), tb, 0, stream, Wq, WTqh, WTql, E_, E_);
    hipLaunchKernelGGL(tconv_split_kernel, dim3(1024), tb, 0, stream, Wk,
                       WTqh + (size_t)1024*1024, WTql + (size_t)1024*1024, E_, E_);
    hipLaunchKernelGGL(tconv_kernel, dim3(1024), tb, 0, stream, Wv, WTvg, E_, E_);
    hipLaunchKernelGGL(tconv_kernel, dim3(1024), tb, 0, stream, Wg, WTvg + (size_t)1024*1024, E_, E_);
    hipLaunchKernelGGL(tconv_kernel, dim3(1024), tb, 0, stream, Wo, WTo, E_, E_);

    // fused projections
    hipLaunchKernelGGL(gemm_qk_kernel, dim3(512), dim3(256), 0, stream,
                       xh, xl, WTqh, WTql, qhb, qlb, khb, klb);
    hipLaunchKernelGGL(gemm_vg_kernel, dim3(512), dim3(256), 0, stream,
                       xh, WTvg, vt, Gf);

    // attention + RMSNorm + gate
    hipLaunchKernelGGL(attn_kernel, dim3(512), dim3(256), 0, stream,
                       qhb, qlb, khb, klb, vt, cl, Gf, rms_w, Yb);

    // output projection
    hipLaunchKernelGGL(gemm_out_kernel, dim3(512), dim3(256), 0, stream, Yb, WTo, out);
}

// Round 6
// 245.015 us; speedup vs baseline: 2.0909x; 1.0356x over previous
//
#include <hip/hip_runtime.h>
#include <hip/hip_bf16.h>
#include <math.h>

#define B_ 2
#define T_ 2048
#define E_ 1024
#define H_ 16
#define D_ 64
#define MTOK (B_*T_)   // 4096

typedef __bf16 bf16;
typedef __bf16 bf16x8 __attribute__((ext_vector_type(8)));
typedef __bf16 bf16x4 __attribute__((ext_vector_type(4)));
typedef float  f32x4  __attribute__((ext_vector_type(4)));

__device__ __forceinline__ void gl_lds16(const void* g, void* l) {
    __builtin_amdgcn_global_load_lds(
        (const __attribute__((address_space(1))) void*)g,
        (__attribute__((address_space(3))) void*)l, 16, 0, 0);
}

// ---------------- f32 -> bf16 hi/lo split elementwise (16B stores) ----------------
__global__ __launch_bounds__(256) void f2b_split_kernel(const float* __restrict__ s,
                                                        bf16* __restrict__ hi,
                                                        bf16* __restrict__ lo, int n) {
    int i = (blockIdx.x * 256 + threadIdx.x) * 8;
    if (i + 7 < n) {
        float4 a = *(const float4*)(s + i);
        float4 b = *(const float4*)(s + i + 4);
        float va[8] = {a.x, a.y, a.z, a.w, b.x, b.y, b.z, b.w};
        bf16x8 hv, lv;
#pragma unroll
        for (int j = 0; j < 8; ++j) {
            bf16 h = (bf16)va[j];
            hv[j] = h;
            lv[j] = (bf16)(va[j] - (float)h);
        }
        *(bf16x8*)(hi + i) = hv;
        *(bf16x8*)(lo + i) = lv;
    }
}

// ---- all weight transposes in ONE launch: seg 0,1 split (Wq,Wk); 2,3,4 plain ----
__global__ void prep_weights_kernel(const float* __restrict__ Wq, const float* __restrict__ Wk,
                                    const float* __restrict__ Wv, const float* __restrict__ Wg,
                                    const float* __restrict__ Wo,
                                    bf16* __restrict__ WTqh, bf16* __restrict__ WTql,
                                    bf16* __restrict__ WTvg, bf16* __restrict__ WTo) {
    __shared__ float t[32][33];
    const int seg = blockIdx.x >> 10;            // 5 segments x 1024 blocks
    const int bid = blockIdx.x & 1023;
    const float* src = (seg == 0) ? Wq : (seg == 1) ? Wk : (seg == 2) ? Wv
                     : (seg == 3) ? Wg : Wo;
    const int bx = bid & 31, by = bid >> 5;      // 1024/32 = 32 tiles per dim
    const int tx = threadIdx.x, ty = threadIdx.y;
#pragma unroll
    for (int i = ty; i < 32; i += 8)
        t[i][tx] = src[(size_t)(by*32 + i)*1024 + bx*32 + tx];
    __syncthreads();
    if (seg < 2) {
        bf16* dh = WTqh + (size_t)seg*1024*1024;
        bf16* dl = WTql + (size_t)seg*1024*1024;
#pragma unroll
        for (int i = ty; i < 32; i += 8) {
            float v = t[tx][i];
            bf16 h = (bf16)v;
            size_t idx = (size_t)(bx*32 + i)*1024 + by*32 + tx;
            dh[idx] = h;
            dl[idx] = (bf16)(v - (float)h);
        }
    } else {
        bf16* dst = (seg == 2) ? WTvg : (seg == 3) ? (WTvg + (size_t)1024*1024) : WTo;
#pragma unroll
        for (int i = ty; i < 32; i += 8)
            dst[(size_t)(bx*32 + i)*1024 + by*32 + tx] = (bf16)t[tx][i];
    }
}

// ---------------- Wa [1024][16] f32 -> WaT [16][1024] f32 ----------------
__global__ __launch_bounds__(256) void waT_kernel(const float* __restrict__ Wa,
                                                  float* __restrict__ WaT) {
    int idx = blockIdx.x * 256 + threadIdx.x;    // grid 64 -> 16384
    int h = idx >> 10, k = idx & 1023;
    WaT[idx] = Wa[k*H_ + h];
}

// ---------------- dt -> log(alpha + 1e-8): LDS-staged x, 16 tokens/block ----------------
__global__ __launch_bounds__(256) void dt_kernel(const float* __restrict__ x,
                                                 const float* __restrict__ WaT,
                                                 const float* __restrict__ A_log,
                                                 const float* __restrict__ dt_bias,
                                                 float* __restrict__ lg) {
    __shared__ float xs[16][1032];               // pad 8 -> token banks {0,8,16,24}
    const int tb = blockIdx.x * 16;              // grid 256
    const int tid = threadIdx.x;
#pragma unroll
    for (int v = tid; v < 4096; v += 256) {
        int row = v >> 8, c4 = (v & 255) * 4;
        float4 val = *(const float4*)(x + (size_t)(tb + row)*E_ + c4);
        xs[row][c4+0] = val.x; xs[row][c4+1] = val.y;
        xs[row][c4+2] = val.z; xs[row][c4+3] = val.w;
    }
    __syncthreads();
    const int i = tid >> 4, h = tid & 15;
    const float* wrow = WaT + (size_t)h*1024;
    float acc = 0.f;
#pragma unroll 8
    for (int k = 0; k < 1024; k += 4) {
        float4 xv = *(const float4*)&xs[i][k];
        float4 wv = *(const float4*)(wrow + k);
        acc += xv.x*wv.x + xv.y*wv.y + xv.z*wv.z + xv.w*wv.w;
    }
    float z   = acc + dt_bias[h];
    float dtv = (z > 20.f) ? z : log1pf(expf(z));
    float la  = -expf(A_log[h]) * dtv;
    float l   = logf(expf(la) + 1e-8f);
    int n = tb + i;
    int b = n / T_, t = n % T_;
    lg[(size_t)(b*H_ + h)*T_ + t] = l;
}

// ---------------- f64 inclusive scan of lg rows -> cl ----------------
__global__ __launch_bounds__(256) void scan_kernel(const float* __restrict__ lg,
                                                   double* __restrict__ cl) {
    int row = blockIdx.x, tid = threadIdx.x;
    __shared__ double ls[256];
    const float* p = lg + (size_t)row*T_ + tid*8;
    double loc[8], s = 0.0;
#pragma unroll
    for (int j = 0; j < 8; ++j) { s += (double)p[j]; loc[j] = s; }
    ls[tid] = s;
    __syncthreads();
    for (int off = 1; off < 256; off <<= 1) {
        double add = (tid >= off) ? ls[tid - off] : 0.0;
        __syncthreads();
        ls[tid] += add;
        __syncthreads();
    }
    double prefix = ls[tid] - s;
    double* o = cl + (size_t)row*T_ + tid*8;
#pragma unroll
    for (int j = 0; j < 8; ++j) o[j] = prefix + loc[j];
}

// ---- fused split GEMM (Q|K) N=2048 + L2-norm + hi/lo split epilogue ----
__global__ __launch_bounds__(256) void gemm_qk_kernel(
    const bf16* __restrict__ Ah, const bf16* __restrict__ Al,
    const bf16* __restrict__ Bh, const bf16* __restrict__ Bl,
    bf16* __restrict__ qhb, bf16* __restrict__ qlb,
    bf16* __restrict__ khb, bf16* __restrict__ klb) {
    const int K = E_;
    __shared__ __align__(16) bf16 Ash[128*32];
    __shared__ __align__(16) bf16 Asl[128*32];
    __shared__ __align__(16) bf16 Bsh[128*32];
    __shared__ __align__(16) bf16 Bsl[128*32];
    int bid = blockIdx.x;
    bid = (bid & 7) * 64 + (bid >> 3);           // XCD swizzle, 512 blocks
    const int bx = bid & 15, by = bid >> 4;      // nbx = 2048/128 = 16
    const int tid = threadIdx.x, lane = tid & 63, wid = tid >> 6;
    const int wr = wid >> 1, wc = wid & 1;
    f32x4 acc[4][4];
#pragma unroll
    for (int m = 0; m < 4; ++m)
#pragma unroll
        for (int n = 0; n < 4; ++n) acc[m][n] = (f32x4)0.0f;
    const int tr = tid >> 2;
    const int tc = (tid & 3) * 8;
    for (int k0 = 0; k0 < K; k0 += 32) {
#pragma unroll
        for (int i = 0; i < 2; ++i) {
            size_t ga = (size_t)(by*128 + i*64 + tr)*K + k0 + tc;
            size_t gb = (size_t)(bx*128 + i*64 + tr)*K + k0 + tc;
            gl_lds16(Ah + ga, &Ash[(i*256 + wid*64)*8]);
            gl_lds16(Al + ga, &Asl[(i*256 + wid*64)*8]);
            gl_lds16(Bh + gb, &Bsh[(i*256 + wid*64)*8]);
            gl_lds16(Bl + gb, &Bsl[(i*256 + wid*64)*8]);
        }
        __syncthreads();
        bf16x8 ah[4], al[4], bh[4], bl[4];
#pragma unroll
        for (int m = 0; m < 4; ++m) {
            int o = (wr*64 + m*16 + (lane&15))*32 + ((lane>>4)*8);
            ah[m] = *(const bf16x8*)&Ash[o];
            al[m] = *(const bf16x8*)&Asl[o];
        }
#pragma unroll
        for (int n = 0; n < 4; ++n) {
            int o = (wc*64 + n*16 + (lane&15))*32 + ((lane>>4)*8);
            bh[n] = *(const bf16x8*)&Bsh[o];
            bl[n] = *(const bf16x8*)&Bsl[o];
        }
#pragma unroll
        for (int m = 0; m < 4; ++m)
#pragma unroll
            for (int n = 0; n < 4; ++n) {
                acc[m][n] = __builtin_amdgcn_mfma_f32_16x16x32_bf16(al[m], bh[n], acc[m][n], 0, 0, 0);
                acc[m][n] = __builtin_amdgcn_mfma_f32_16x16x32_bf16(ah[m], bl[n], acc[m][n], 0, 0, 0);
                acc[m][n] = __builtin_amdgcn_mfma_f32_16x16x32_bf16(ah[m], bh[n], acc[m][n], 0, 0, 0);
            }
        __syncthreads();
    }
    // epilogue: this wave's 64 cols = exactly one head
    const int headg = bx*2 + wc;                 // 0..31
    bf16* dh = (headg < 16) ? qhb : khb;
    bf16* dl = (headg < 16) ? qlb : klb;
    const int h = headg & 15;
    const int lr = lane & 15, lg4 = lane >> 4;
#pragma unroll
    for (int m = 0; m < 4; ++m)
#pragma unroll
        for (int r = 0; r < 4; ++r) {
            float ss = acc[m][0][r]*acc[m][0][r] + acc[m][1][r]*acc[m][1][r]
                     + acc[m][2][r]*acc[m][2][r] + acc[m][3][r]*acc[m][3][r];
#pragma unroll
            for (int off = 1; off < 16; off <<= 1) ss += __shfl_xor(ss, off, 64);
            float sc = 1.0f / fmaxf(sqrtf(ss), 1e-12f);
            int token = by*128 + wr*64 + m*16 + lg4*4 + r;
#pragma unroll
            for (int n = 0; n < 4; ++n) {
                int d = n*16 + lr;
                float qv = acc[m][n][r] * sc;
                bf16 hv = (bf16)qv;
                size_t idx = ((size_t)token*H_ + h)*64 + d;
                dh[idx] = hv;
                dl[idx] = (bf16)(qv - (float)hv);
            }
        }
}

// ---- plain GEMM (V|G) N=2048 + transposed-V / silu-G epilogue ----
__global__ __launch_bounds__(256) void gemm_vg_kernel(
    const bf16* __restrict__ A, const bf16* __restrict__ BT,
    bf16* __restrict__ vt, float* __restrict__ Gf) {
    const int K = E_;
    __shared__ __align__(16) bf16 As[128*32];
    __shared__ __align__(16) bf16 Bs[128*32];
    int bid = blockIdx.x;
    bid = (bid & 7) * 64 + (bid >> 3);           // XCD swizzle, 512 blocks
    const int bx = bid & 15, by = bid >> 4;
    const int tid = threadIdx.x, lane = tid & 63, wid = tid >> 6;
    const int wr = wid >> 1, wc = wid & 1;
    f32x4 acc[4][4];
#pragma unroll
    for (int m = 0; m < 4; ++m)
#pragma unroll
        for (int n = 0; n < 4; ++n) acc[m][n] = (f32x4)0.0f;
    const int tr = tid >> 2;
    const int tc = (tid & 3) * 8;
    for (int k0 = 0; k0 < K; k0 += 32) {
#pragma unroll
        for (int i = 0; i < 2; ++i) {
            gl_lds16(A  + (size_t)(by*128 + i*64 + tr)*K + k0 + tc, &As[(i*256 + wid*64)*8]);
            gl_lds16(BT + (size_t)(bx*128 + i*64 + tr)*K + k0 + tc, &Bs[(i*256 + wid*64)*8]);
        }
        __syncthreads();
        bf16x8 af[4], bfr[4];
#pragma unroll
        for (int m = 0; m < 4; ++m)
            af[m] = *(const bf16x8*)&As[(wr*64 + m*16 + (lane&15))*32 + ((lane>>4)*8)];
#pragma unroll
        for (int n = 0; n < 4; ++n)
            bfr[n] = *(const bf16x8*)&Bs[(wc*64 + n*16 + (lane&15))*32 + ((lane>>4)*8)];
#pragma unroll
        for (int m = 0; m < 4; ++m)
#pragma unroll
            for (int n = 0; n < 4; ++n)
                acc[m][n] = __builtin_amdgcn_mfma_f32_16x16x32_bf16(af[m], bfr[n], acc[m][n], 0, 0, 0);
        __syncthreads();
    }
    const int lr = lane & 15, lg4 = lane >> 4;
    const int colbase = bx*128 + wc*64;
    const int b = by >> 4;                       // 128-row tile lies in one batch
    if (colbase < 1024) {
        // V half: write vt[(b*H+head)*64 + d][t] (bf16, 4 tokens packed)
        const int head = colbase >> 6;
#pragma unroll
        for (int m = 0; m < 4; ++m) {
            int trow = by*128 + wr*64 + m*16 + lg4*4;
            int tloc = trow - b*T_;
#pragma unroll
            for (int n = 0; n < 4; ++n) {
                int d = n*16 + lr;
                bf16x4 pk;
                pk[0] = (bf16)acc[m][n][0]; pk[1] = (bf16)acc[m][n][1];
                pk[2] = (bf16)acc[m][n][2]; pk[3] = (bf16)acc[m][n][3];
                *(bf16x4*)(vt + ((size_t)((b*H_ + head)*64 + d))*T_ + tloc) = pk;
            }
        }
    } else {
        // G half: silu, write f32 [token][E]
#pragma unroll
        for (int m = 0; m < 4; ++m)
#pragma unroll
            for (int r = 0; r < 4; ++r) {
                int token = by*128 + wr*64 + m*16 + lg4*4 + r;
#pragma unroll
                for (int n = 0; n < 4; ++n) {
                    int colg = colbase - 1024 + n*16 + lr;
                    float g = acc[m][n][r];
                    Gf[(size_t)token*E_ + colg] = g / (1.0f + __expf(-g));
                }
            }
    }
}

// ---- output GEMM: out f32 = Yb bf16 @ WoT, 128x64 tile ----
__global__ __launch_bounds__(256) void gemm_out_kernel(
    const bf16* __restrict__ A, const bf16* __restrict__ BT, float* __restrict__ C) {
    const int K = E_, N = E_;
    __shared__ __align__(16) bf16 As[128*32];
    __shared__ __align__(16) bf16 Bs[64*32];
    int bid = blockIdx.x;
    bid = (bid & 7) * 64 + (bid >> 3);           // XCD swizzle, 512 blocks
    const int bx = bid & 15, by = bid >> 4;      // nbx = 1024/64 = 16
    const int tid = threadIdx.x, lane = tid & 63, wid = tid >> 6;
    const int wr = wid >> 1, wc = wid & 1;       // waves 64x32
    f32x4 acc[4][2];
#pragma unroll
    for (int m = 0; m < 4; ++m)
#pragma unroll
        for (int n = 0; n < 2; ++n) acc[m][n] = (f32x4)0.0f;
    const int tr = tid >> 2;
    const int tc = (tid & 3) * 8;
    for (int k0 = 0; k0 < K; k0 += 32) {
#pragma unroll
        for (int i = 0; i < 2; ++i)
            gl_lds16(A + (size_t)(by*128 + i*64 + tr)*K + k0 + tc, &As[(i*256 + wid*64)*8]);
        gl_lds16(BT + (size_t)(bx*64 + tid/4)*K + k0 + tc, &Bs[(wid*64)*8]);
        __syncthreads();
        bf16x8 af[4], bfr[2];
#pragma unroll
        for (int m = 0; m < 4; ++m)
            af[m] = *(const bf16x8*)&As[(wr*64 + m*16 + (lane&15))*32 + ((lane>>4)*8)];
#pragma unroll
        for (int n = 0; n < 2; ++n)
            bfr[n] = *(const bf16x8*)&Bs[(wc*32 + n*16 + (lane&15))*32 + ((lane>>4)*8)];
#pragma unroll
        for (int m = 0; m < 4; ++m)
#pragma unroll
            for (int n = 0; n < 2; ++n)
                acc[m][n] = __builtin_amdgcn_mfma_f32_16x16x32_bf16(af[m], bfr[n], acc[m][n], 0, 0, 0);
        __syncthreads();
    }
    const int crow = by*128 + wr*64;
    const int ccol = bx*64 + wc*32 + (lane & 15);
#pragma unroll
    for (int m = 0; m < 4; ++m)
#pragma unroll
        for (int r = 0; r < 4; ++r) {
            int row = crow + m*16 + (lane>>4)*4 + r;
#pragma unroll
            for (int n = 0; n < 2; ++n)
                C[(size_t)row*N + ccol + n*16] = acc[m][n][r];
        }
}

// ---- decay attention: QBLK=128, double-buffered prefetch, balanced grid ----
__global__ __launch_bounds__(256) void attn_kernel(
    const bf16* __restrict__ qh, const bf16* __restrict__ ql,
    const bf16* __restrict__ kh, const bf16* __restrict__ kl,
    const bf16* __restrict__ vt, const double* __restrict__ cl,
    const float* __restrict__ Gf, const float* __restrict__ rms_w,
    bf16* __restrict__ Y) {
    __shared__ __align__(16) bf16 Ksh[2][64*64];  // [key][d] swizzled, ping-pong
    __shared__ __align__(16) bf16 Ksl[2][64*64];
    __shared__ __align__(16) bf16 Vs[2][64*64];   // [d][key] swizzled, ping-pong
    __shared__ __align__(16) bf16 Ps[128*64];     // [qrow][key] swizzled
    const int rank = blockIdx.x >> 5, bh = blockIdx.x & 31;
    // CU gets ranks (r, r+8): it pairs sum to 15 -> uniform per-CU work; heavy first
    const int it = (rank < 8) ? (15 - rank) : (rank - 8);
    const int b = bh >> 4, h = bh & 15;
    const int tid = threadIdx.x, lane = tid & 63, wid = tid >> 6;
    const int i0 = it * 128;
    const int lr = lane & 15, lg4 = lane >> 4;
    // Q fragments: wave owns rows i0 + wid*32 .. +32 (2 m-frags)
    bf16x8 qfh[2][2], qfl[2][2];
#pragma unroll
    for (int mm = 0; mm < 2; ++mm) {
        int qtok = i0 + wid*32 + mm*16 + lr;
        size_t qa = (size_t)(b*T_ + qtok)*E_ + h*64 + lg4*8;
        qfh[mm][0] = *(const bf16x8*)(qh + qa);
        qfh[mm][1] = *(const bf16x8*)(qh + qa + 32);
        qfl[mm][0] = *(const bf16x8*)(ql + qa);
        qfl[mm][1] = *(const bf16x8*)(ql + qa + 32);
    }
    const double* clrow = cl + (size_t)bh*T_;
    const double base = clrow[i0];
    // f32 decay exponents relative to tile base (relative L error <=0.2%, not amplified)
    float cli2[2][4];
#pragma unroll
    for (int mm = 0; mm < 2; ++mm)
#pragma unroll
        for (int r = 0; r < 4; ++r)
            cli2[mm][r] = (float)(clrow[i0 + wid*32 + mm*16 + lg4*4 + r] - base);
    f32x4 oacc[2][4];
#pragma unroll
    for (int mm = 0; mm < 2; ++mm)
#pragma unroll
        for (int n = 0; n < 4; ++n) oacc[mm][n] = (f32x4)0.0f;
    const int srow8 = lane >> 3;                 // 0..7 within 8-row group
    const int csrc  = (lane & 7) ^ srow8;        // pre-swizzled source chunk
    auto STAGE = [&](int jt, int buf) {
        const int j0 = jt * 64;
#pragma unroll
        for (int i = 0; i < 2; ++i) {
            int krow = j0 + i*32 + wid*8 + srow8;
            int drow = i*32 + wid*8 + srow8;
            size_t gk = (size_t)(b*T_ + krow)*E_ + h*64 + csrc*8;
            gl_lds16(kh + gk, &Ksh[buf][(i*32 + wid*8)*64]);
            gl_lds16(kl + gk, &Ksl[buf][(i*32 + wid*8)*64]);
            gl_lds16(vt + (size_t)(bh*64 + drow)*T_ + j0 + csrc*8, &Vs[buf][(i*32 + wid*8)*64]);
        }
    };
    const int niter = 2*it + 2;
    STAGE(0, 0);
    __syncthreads();
    int cur = 0;
    for (int jt = 0; jt < niter; ++jt) {
        const int j0 = jt * 64;
        if (jt + 1 < niter) STAGE(jt + 1, cur ^ 1);   // prefetch overlaps compute
        // S = (qh+ql)(kh+kl)^T (3 products), decay+mask, write P (own rows)
#pragma unroll
        for (int n = 0; n < 4; ++n) {
            const int r = n*16 + lr;             // key row in tile
            const int sw = r & 7;
            const int ko = r*64;
            bf16x8 k_h0 = *(const bf16x8*)&Ksh[cur][ko + ((lg4 ^ sw)*8)];
            bf16x8 k_h1 = *(const bf16x8*)&Ksh[cur][ko + (((lg4+4) ^ sw)*8)];
            bf16x8 k_l0 = *(const bf16x8*)&Ksl[cur][ko + ((lg4 ^ sw)*8)];
            bf16x8 k_l1 = *(const bf16x8*)&Ksl[cur][ko + (((lg4+4) ^ sw)*8)];
            const int j = j0 + r;                // global key index
            const float cj = (float)(clrow[j] - base);
#pragma unroll
            for (int mm = 0; mm < 2; ++mm) {
                f32x4 s = (f32x4)0.0f;
                s = __builtin_amdgcn_mfma_f32_16x16x32_bf16(qfl[mm][0], k_h0, s, 0, 0, 0);
                s = __builtin_amdgcn_mfma_f32_16x16x32_bf16(qfl[mm][1], k_h1, s, 0, 0, 0);
                s = __builtin_amdgcn_mfma_f32_16x16x32_bf16(qfh[mm][0], k_l0, s, 0, 0, 0);
                s = __builtin_amdgcn_mfma_f32_16x16x32_bf16(qfh[mm][1], k_l1, s, 0, 0, 0);
                s = __builtin_amdgcn_mfma_f32_16x16x32_bf16(qfh[mm][0], k_h0, s, 0, 0, 0);
                s = __builtin_amdgcn_mfma_f32_16x16x32_bf16(qfh[mm][1], k_h1, s, 0, 0, 0);
                const int prbase = wid*32 + mm*16 + lg4*4;
#pragma unroll
                for (int r4 = 0; r4 < 4; ++r4) {
                    const int pr = prbase + r4;
                    const int qrow = i0 + pr;
                    float val = (j <= qrow)
                        ? s[r4] * __expf(cli2[mm][r4] - cj) : 0.0f;
                    const int cw = n*2 + (lr >> 3);
                    Ps[pr*64 + ((cw ^ (pr & 7))*8) + (lane & 7)] = (bf16)val;
                }
            }
        }
        // O += P V  (same-wave P round trip; lgkmcnt ordering suffices)
#pragma unroll
        for (int kk = 0; kk < 2; ++kk) {
            const int js = kk*4 + lg4;
            bf16x8 pf[2];
#pragma unroll
            for (int mm = 0; mm < 2; ++mm) {
                const int rp = wid*32 + mm*16 + lr;
                pf[mm] = *(const bf16x8*)&Ps[rp*64 + ((js ^ (rp & 7))*8)];
            }
#pragma unroll
            for (int n = 0; n < 4; ++n) {
                const int rv = n*16 + lr;
                bf16x8 vf = *(const bf16x8*)&Vs[cur][rv*64 + ((js ^ (rv & 7))*8)];
                oacc[0][n] = __builtin_amdgcn_mfma_f32_16x16x32_bf16(pf[0], vf, oacc[0][n], 0, 0, 0);
                oacc[1][n] = __builtin_amdgcn_mfma_f32_16x16x32_bf16(pf[1], vf, oacc[1][n], 0, 0, 0);
            }
        }
        __syncthreads();                         // drains prefetch vmcnt + Ps/Vs reads
        cur ^= 1;
    }
    // epilogue: RMSNorm over d=64, * rms_w, * pre-silu'd gate -> bf16 Y
#pragma unroll
    for (int mm = 0; mm < 2; ++mm)
#pragma unroll
        for (int r = 0; r < 4; ++r) {
            float ss = oacc[mm][0][r]*oacc[mm][0][r] + oacc[mm][1][r]*oacc[mm][1][r]
                     + oacc[mm][2][r]*oacc[mm][2][r] + oacc[mm][3][r]*oacc[mm][3][r];
#pragma unroll
            for (int off = 1; off < 16; off <<= 1) ss += __shfl_xor(ss, off, 64);
            const float scale = rsqrtf(ss * (1.0f/64.0f) + 1e-6f);
            const int gtok = b*T_ + i0 + wid*32 + mm*16 + lg4*4 + r;
#pragma unroll
            for (int n = 0; n < 4; ++n) {
                const int d = n*16 + lr;
                float o = oacc[mm][n][r] * scale * rms_w[d];
                float gate = Gf[(size_t)gtok*E_ + h*64 + d];
                Y[(size_t)gtok*E_ + h*64 + d] = (bf16)(o * gate);
            }
        }
}

extern "C" void kernel_launch(void* const* d_in, const int* in_sizes, int n_in,
                              void* d_out, int out_size, void* d_ws, size_t ws_size,
                              hipStream_t stream) {
    const float* x       = (const float*)d_in[0];
    const float* Wq      = (const float*)d_in[1];
    const float* Wk      = (const float*)d_in[2];
    const float* Wv      = (const float*)d_in[3];
    const float* Wa      = (const float*)d_in[4];
    const float* Wg      = (const float*)d_in[5];
    const float* Wo      = (const float*)d_in[6];
    const float* A_log   = (const float*)d_in[7];
    const float* dt_bias = (const float*)d_in[8];
    const float* rms_w   = (const float*)d_in[9];
    float* out = (float*)d_out;

    char* w = (char*)d_ws;
    size_t off = 0;
    auto alloc = [&](size_t bytes) {
        void* p = w + off; off += (bytes + 255) & ~(size_t)255; return p;
    };
    bf16*   xh   = (bf16*)  alloc((size_t)MTOK*E_*2);
    bf16*   xl   = (bf16*)  alloc((size_t)MTOK*E_*2);
    bf16*   WTqh = (bf16*)  alloc((size_t)2048*E_*2);
    bf16*   WTql = (bf16*)  alloc((size_t)2048*E_*2);
    bf16*   WTvg = (bf16*)  alloc((size_t)2048*E_*2);
    bf16*   WTo  = (bf16*)  alloc((size_t)E_*E_*2);
    bf16*   qhb  = (bf16*)  alloc((size_t)MTOK*E_*2);
    bf16*   qlb  = (bf16*)  alloc((size_t)MTOK*E_*2);
    bf16*   khb  = (bf16*)  alloc((size_t)MTOK*E_*2);
    bf16*   klb  = (bf16*)  alloc((size_t)MTOK*E_*2);
    bf16*   vt   = (bf16*)  alloc((size_t)MTOK*E_*2);
    float*  Gf   = (float*) alloc((size_t)MTOK*E_*4);
    float*  lg   = (float*) alloc((size_t)B_*H_*T_*4);
    double* cl   = (double*)alloc((size_t)B_*H_*T_*8);
    bf16*   Yb   = (bf16*)  alloc((size_t)MTOK*E_*2);
    float*  WaT  = (float*) alloc((size_t)H_*E_*4);

    hipLaunchKernelGGL(f2b_split_kernel, dim3(MTOK*E_/2048), dim3(256), 0, stream, x, xh, xl, MTOK*E_);
    hipLaunchKernelGGL(waT_kernel, dim3(64), dim3(256), 0, stream, Wa, WaT);
    hipLaunchKernelGGL(dt_kernel,  dim3(256), dim3(256), 0, stream, x, WaT, A_log, dt_bias, lg);
    hipLaunchKernelGGL(scan_kernel, dim3(B_*H_), dim3(256), 0, stream, lg, cl);

    // all weight transposes in one launch
    hipLaunchKernelGGL(prep_weights_kernel, dim3(5120), dim3(32, 8), 0, stream,
                       Wq, Wk, Wv, Wg, Wo, WTqh, WTql, WTvg, WTo);

    // fused projections
    hipLaunchKernelGGL(gemm_qk_kernel, dim3(512), dim3(256), 0, stream,
                       xh, xl, WTqh, WTql, qhb, qlb, khb, klb);
    hipLaunchKernelGGL(gemm_vg_kernel, dim3(512), dim3(256), 0, stream,
                       xh, WTvg, vt, Gf);

    // attention + RMSNorm + gate
    hipLaunchKernelGGL(attn_kernel, dim3(512), dim3(256), 0, stream,
                       qhb, qlb, khb, klb, vt, cl, Gf, rms_w, Yb);

    // output projection
    hipLaunchKernelGGL(gemm_out_kernel, dim3(512), dim3(256), 0, stream, Yb, WTo, out);
}

// Round 7
// 180.659 us; speedup vs baseline: 2.8357x; 1.3562x over previous
//
#include <hip/hip_runtime.h>
#include <hip/hip_bf16.h>
#include <math.h>

#define B_ 2
#define T_ 2048
#define E_ 1024
#define H_ 16
#define D_ 64
#define MTOK (B_*T_)   // 4096

typedef __bf16 bf16;
typedef __bf16 bf16x8 __attribute__((ext_vector_type(8)));
typedef __bf16 bf16x4 __attribute__((ext_vector_type(4)));
typedef float  f32x4  __attribute__((ext_vector_type(4)));

__device__ __forceinline__ void gl_lds16(const void* g, void* l) {
    __builtin_amdgcn_global_load_lds(
        (const __attribute__((address_space(1))) void*)g,
        (__attribute__((address_space(3))) void*)l, 16, 0, 0);
}

// ---------------- f32 -> bf16 hi/lo split elementwise (16B stores) ----------------
__global__ __launch_bounds__(256) void f2b_split_kernel(const float* __restrict__ s,
                                                        bf16* __restrict__ hi,
                                                        bf16* __restrict__ lo, int n) {
    int i = (blockIdx.x * 256 + threadIdx.x) * 8;
    if (i + 7 < n) {
        float4 a = *(const float4*)(s + i);
        float4 b = *(const float4*)(s + i + 4);
        float va[8] = {a.x, a.y, a.z, a.w, b.x, b.y, b.z, b.w};
        bf16x8 hv, lv;
#pragma unroll
        for (int j = 0; j < 8; ++j) {
            bf16 h = (bf16)va[j];
            hv[j] = h;
            lv[j] = (bf16)(va[j] - (float)h);
        }
        *(bf16x8*)(hi + i) = hv;
        *(bf16x8*)(lo + i) = lv;
    }
}

// ---- all weight transposes in ONE launch: seg 0,1 split (Wq,Wk); 2,3,4 plain ----
__global__ void prep_weights_kernel(const float* __restrict__ Wq, const float* __restrict__ Wk,
                                    const float* __restrict__ Wv, const float* __restrict__ Wg,
                                    const float* __restrict__ Wo,
                                    bf16* __restrict__ WTqh, bf16* __restrict__ WTql,
                                    bf16* __restrict__ WTvg, bf16* __restrict__ WTo) {
    __shared__ float t[32][33];
    const int seg = blockIdx.x >> 10;            // 5 segments x 1024 blocks
    const int bid = blockIdx.x & 1023;
    const float* src = (seg == 0) ? Wq : (seg == 1) ? Wk : (seg == 2) ? Wv
                     : (seg == 3) ? Wg : Wo;
    const int bx = bid & 31, by = bid >> 5;      // 1024/32 = 32 tiles per dim
    const int tx = threadIdx.x, ty = threadIdx.y;
#pragma unroll
    for (int i = ty; i < 32; i += 8)
        t[i][tx] = src[(size_t)(by*32 + i)*1024 + bx*32 + tx];
    __syncthreads();
    if (seg < 2) {
        bf16* dh = WTqh + (size_t)seg*1024*1024;
        bf16* dl = WTql + (size_t)seg*1024*1024;
#pragma unroll
        for (int i = ty; i < 32; i += 8) {
            float v = t[tx][i];
            bf16 h = (bf16)v;
            size_t idx = (size_t)(bx*32 + i)*1024 + by*32 + tx;
            dh[idx] = h;
            dl[idx] = (bf16)(v - (float)h);
        }
    } else {
        bf16* dst = (seg == 2) ? WTvg : (seg == 3) ? (WTvg + (size_t)1024*1024) : WTo;
#pragma unroll
        for (int i = ty; i < 32; i += 8)
            dst[(size_t)(bx*32 + i)*1024 + by*32 + tx] = (bf16)t[tx][i];
    }
}

// ---------------- Wa [1024][16] f32 -> WaT [16][1024] f32 ----------------
__global__ __launch_bounds__(256) void waT_kernel(const float* __restrict__ Wa,
                                                  float* __restrict__ WaT) {
    int idx = blockIdx.x * 256 + threadIdx.x;    // grid 64 -> 16384
    int h = idx >> 10, k = idx & 1023;
    WaT[idx] = Wa[k*H_ + h];
}

// ---------------- dt -> log(alpha + 1e-8): LDS-staged x, 16 tokens/block ----------------
__global__ __launch_bounds__(256) void dt_kernel(const float* __restrict__ x,
                                                 const float* __restrict__ WaT,
                                                 const float* __restrict__ A_log,
                                                 const float* __restrict__ dt_bias,
                                                 float* __restrict__ lg) {
    __shared__ float xs[16][1032];               // pad 8 -> token banks {0,8,16,24}
    const int tb = blockIdx.x * 16;              // grid 256
    const int tid = threadIdx.x;
#pragma unroll
    for (int v = tid; v < 4096; v += 256) {
        int row = v >> 8, c4 = (v & 255) * 4;
        float4 val = *(const float4*)(x + (size_t)(tb + row)*E_ + c4);
        xs[row][c4+0] = val.x; xs[row][c4+1] = val.y;
        xs[row][c4+2] = val.z; xs[row][c4+3] = val.w;
    }
    __syncthreads();
    const int i = tid >> 4, h = tid & 15;
    const float* wrow = WaT + (size_t)h*1024;
    float acc = 0.f;
#pragma unroll 8
    for (int k = 0; k < 1024; k += 4) {
        float4 xv = *(const float4*)&xs[i][k];
        float4 wv = *(const float4*)(wrow + k);
        acc += xv.x*wv.x + xv.y*wv.y + xv.z*wv.z + xv.w*wv.w;
    }
    float z   = acc + dt_bias[h];
    float dtv = (z > 20.f) ? z : log1pf(expf(z));
    float la  = -expf(A_log[h]) * dtv;
    float l   = logf(expf(la) + 1e-8f);
    int n = tb + i;
    int b = n / T_, t = n % T_;
    lg[(size_t)(b*H_ + h)*T_ + t] = l;
}

// ---------------- f64 inclusive scan of lg rows -> cl ----------------
__global__ __launch_bounds__(256) void scan_kernel(const float* __restrict__ lg,
                                                   double* __restrict__ cl) {
    int row = blockIdx.x, tid = threadIdx.x;
    __shared__ double ls[256];
    const float* p = lg + (size_t)row*T_ + tid*8;
    double loc[8], s = 0.0;
#pragma unroll
    for (int j = 0; j < 8; ++j) { s += (double)p[j]; loc[j] = s; }
    ls[tid] = s;
    __syncthreads();
    for (int off = 1; off < 256; off <<= 1) {
        double add = (tid >= off) ? ls[tid - off] : 0.0;
        __syncthreads();
        ls[tid] += add;
        __syncthreads();
    }
    double prefix = ls[tid] - s;
    double* o = cl + (size_t)row*T_ + tid*8;
#pragma unroll
    for (int j = 0; j < 8; ++j) o[j] = prefix + loc[j];
}

// ---- fused split GEMM (Q|K) N=2048 + L2-norm + hi/lo split epilogue ----
__global__ __launch_bounds__(256) void gemm_qk_kernel(
    const bf16* __restrict__ Ah, const bf16* __restrict__ Al,
    const bf16* __restrict__ Bh, const bf16* __restrict__ Bl,
    bf16* __restrict__ qhb, bf16* __restrict__ qlb,
    bf16* __restrict__ khb, bf16* __restrict__ klb) {
    const int K = E_;
    __shared__ __align__(16) bf16 Ash[128*32];
    __shared__ __align__(16) bf16 Asl[128*32];
    __shared__ __align__(16) bf16 Bsh[128*32];
    __shared__ __align__(16) bf16 Bsl[128*32];
    int bid = blockIdx.x;
    bid = (bid & 7) * 64 + (bid >> 3);           // XCD swizzle, 512 blocks
    const int bx = bid & 15, by = bid >> 4;      // nbx = 2048/128 = 16
    const int tid = threadIdx.x, lane = tid & 63, wid = tid >> 6;
    const int wr = wid >> 1, wc = wid & 1;
    f32x4 acc[4][4];
#pragma unroll
    for (int m = 0; m < 4; ++m)
#pragma unroll
        for (int n = 0; n < 4; ++n) acc[m][n] = (f32x4)0.0f;
    const int tr = tid >> 2;
    const int tc = (tid & 3) * 8;
    for (int k0 = 0; k0 < K; k0 += 32) {
#pragma unroll
        for (int i = 0; i < 2; ++i) {
            size_t ga = (size_t)(by*128 + i*64 + tr)*K + k0 + tc;
            size_t gb = (size_t)(bx*128 + i*64 + tr)*K + k0 + tc;
            gl_lds16(Ah + ga, &Ash[(i*256 + wid*64)*8]);
            gl_lds16(Al + ga, &Asl[(i*256 + wid*64)*8]);
            gl_lds16(Bh + gb, &Bsh[(i*256 + wid*64)*8]);
            gl_lds16(Bl + gb, &Bsl[(i*256 + wid*64)*8]);
        }
        __syncthreads();
        bf16x8 ah[4], al[4], bh[4], bl[4];
#pragma unroll
        for (int m = 0; m < 4; ++m) {
            int o = (wr*64 + m*16 + (lane&15))*32 + ((lane>>4)*8);
            ah[m] = *(const bf16x8*)&Ash[o];
            al[m] = *(const bf16x8*)&Asl[o];
        }
#pragma unroll
        for (int n = 0; n < 4; ++n) {
            int o = (wc*64 + n*16 + (lane&15))*32 + ((lane>>4)*8);
            bh[n] = *(const bf16x8*)&Bsh[o];
            bl[n] = *(const bf16x8*)&Bsl[o];
        }
#pragma unroll
        for (int m = 0; m < 4; ++m)
#pragma unroll
            for (int n = 0; n < 4; ++n) {
                acc[m][n] = __builtin_amdgcn_mfma_f32_16x16x32_bf16(al[m], bh[n], acc[m][n], 0, 0, 0);
                acc[m][n] = __builtin_amdgcn_mfma_f32_16x16x32_bf16(ah[m], bl[n], acc[m][n], 0, 0, 0);
                acc[m][n] = __builtin_amdgcn_mfma_f32_16x16x32_bf16(ah[m], bh[n], acc[m][n], 0, 0, 0);
            }
        __syncthreads();
    }
    // epilogue: this wave's 64 cols = exactly one head
    const int headg = bx*2 + wc;                 // 0..31
    bf16* dh = (headg < 16) ? qhb : khb;
    bf16* dl = (headg < 16) ? qlb : klb;
    const int h = headg & 15;
    const int lr = lane & 15, lg4 = lane >> 4;
#pragma unroll
    for (int m = 0; m < 4; ++m)
#pragma unroll
        for (int r = 0; r < 4; ++r) {
            float ss = acc[m][0][r]*acc[m][0][r] + acc[m][1][r]*acc[m][1][r]
                     + acc[m][2][r]*acc[m][2][r] + acc[m][3][r]*acc[m][3][r];
#pragma unroll
            for (int off = 1; off < 16; off <<= 1) ss += __shfl_xor(ss, off, 64);
            float sc = 1.0f / fmaxf(sqrtf(ss), 1e-12f);
            int token = by*128 + wr*64 + m*16 + lg4*4 + r;
#pragma unroll
            for (int n = 0; n < 4; ++n) {
                int d = n*16 + lr;
                float qv = acc[m][n][r] * sc;
                bf16 hv = (bf16)qv;
                size_t idx = ((size_t)token*H_ + h)*64 + d;
                dh[idx] = hv;
                dl[idx] = (bf16)(qv - (float)hv);
            }
        }
}

// ---- plain GEMM (V|G) N=2048 + transposed-V / silu-G epilogue ----
__global__ __launch_bounds__(256) void gemm_vg_kernel(
    const bf16* __restrict__ A, const bf16* __restrict__ BT,
    bf16* __restrict__ vt, float* __restrict__ Gf) {
    const int K = E_;
    __shared__ __align__(16) bf16 As[128*32];
    __shared__ __align__(16) bf16 Bs[128*32];
    int bid = blockIdx.x;
    bid = (bid & 7) * 64 + (bid >> 3);           // XCD swizzle, 512 blocks
    const int bx = bid & 15, by = bid >> 4;
    const int tid = threadIdx.x, lane = tid & 63, wid = tid >> 6;
    const int wr = wid >> 1, wc = wid & 1;
    f32x4 acc[4][4];
#pragma unroll
    for (int m = 0; m < 4; ++m)
#pragma unroll
        for (int n = 0; n < 4; ++n) acc[m][n] = (f32x4)0.0f;
    const int tr = tid >> 2;
    const int tc = (tid & 3) * 8;
    for (int k0 = 0; k0 < K; k0 += 32) {
#pragma unroll
        for (int i = 0; i < 2; ++i) {
            gl_lds16(A  + (size_t)(by*128 + i*64 + tr)*K + k0 + tc, &As[(i*256 + wid*64)*8]);
            gl_lds16(BT + (size_t)(bx*128 + i*64 + tr)*K + k0 + tc, &Bs[(i*256 + wid*64)*8]);
        }
        __syncthreads();
        bf16x8 af[4], bfr[4];
#pragma unroll
        for (int m = 0; m < 4; ++m)
            af[m] = *(const bf16x8*)&As[(wr*64 + m*16 + (lane&15))*32 + ((lane>>4)*8)];
#pragma unroll
        for (int n = 0; n < 4; ++n)
            bfr[n] = *(const bf16x8*)&Bs[(wc*64 + n*16 + (lane&15))*32 + ((lane>>4)*8)];
#pragma unroll
        for (int m = 0; m < 4; ++m)
#pragma unroll
            for (int n = 0; n < 4; ++n)
                acc[m][n] = __builtin_amdgcn_mfma_f32_16x16x32_bf16(af[m], bfr[n], acc[m][n], 0, 0, 0);
        __syncthreads();
    }
    const int lr = lane & 15, lg4 = lane >> 4;
    const int colbase = bx*128 + wc*64;
    const int b = by >> 4;                       // 128-row tile lies in one batch
    if (colbase < 1024) {
        // V half: write vt[(b*H+head)*64 + d][t] (bf16, 4 tokens packed)
        const int head = colbase >> 6;
#pragma unroll
        for (int m = 0; m < 4; ++m) {
            int trow = by*128 + wr*64 + m*16 + lg4*4;
            int tloc = trow - b*T_;
#pragma unroll
            for (int n = 0; n < 4; ++n) {
                int d = n*16 + lr;
                bf16x4 pk;
                pk[0] = (bf16)acc[m][n][0]; pk[1] = (bf16)acc[m][n][1];
                pk[2] = (bf16)acc[m][n][2]; pk[3] = (bf16)acc[m][n][3];
                *(bf16x4*)(vt + ((size_t)((b*H_ + head)*64 + d))*T_ + tloc) = pk;
            }
        }
    } else {
        // G half: silu, write f32 [token][E]
#pragma unroll
        for (int m = 0; m < 4; ++m)
#pragma unroll
            for (int r = 0; r < 4; ++r) {
                int token = by*128 + wr*64 + m*16 + lg4*4 + r;
#pragma unroll
                for (int n = 0; n < 4; ++n) {
                    int colg = colbase - 1024 + n*16 + lr;
                    float g = acc[m][n][r];
                    Gf[(size_t)token*E_ + colg] = g / (1.0f + __expf(-g));
                }
            }
    }
}

// ---- output GEMM: out f32 = Yb bf16 @ WoT, 128x64 tile ----
__global__ __launch_bounds__(256) void gemm_out_kernel(
    const bf16* __restrict__ A, const bf16* __restrict__ BT, float* __restrict__ C) {
    const int K = E_, N = E_;
    __shared__ __align__(16) bf16 As[128*32];
    __shared__ __align__(16) bf16 Bs[64*32];
    int bid = blockIdx.x;
    bid = (bid & 7) * 64 + (bid >> 3);           // XCD swizzle, 512 blocks
    const int bx = bid & 15, by = bid >> 4;      // nbx = 1024/64 = 16
    const int tid = threadIdx.x, lane = tid & 63, wid = tid >> 6;
    const int wr = wid >> 1, wc = wid & 1;       // waves 64x32
    f32x4 acc[4][2];
#pragma unroll
    for (int m = 0; m < 4; ++m)
#pragma unroll
        for (int n = 0; n < 2; ++n) acc[m][n] = (f32x4)0.0f;
    const int tr = tid >> 2;
    const int tc = (tid & 3) * 8;
    for (int k0 = 0; k0 < K; k0 += 32) {
#pragma unroll
        for (int i = 0; i < 2; ++i)
            gl_lds16(A + (size_t)(by*128 + i*64 + tr)*K + k0 + tc, &As[(i*256 + wid*64)*8]);
        gl_lds16(BT + (size_t)(bx*64 + tid/4)*K + k0 + tc, &Bs[(wid*64)*8]);
        __syncthreads();
        bf16x8 af[4], bfr[2];
#pragma unroll
        for (int m = 0; m < 4; ++m)
            af[m] = *(const bf16x8*)&As[(wr*64 + m*16 + (lane&15))*32 + ((lane>>4)*8)];
#pragma unroll
        for (int n = 0; n < 2; ++n)
            bfr[n] = *(const bf16x8*)&Bs[(wc*32 + n*16 + (lane&15))*32 + ((lane>>4)*8)];
#pragma unroll
        for (int m = 0; m < 4; ++m)
#pragma unroll
            for (int n = 0; n < 2; ++n)
                acc[m][n] = __builtin_amdgcn_mfma_f32_16x16x32_bf16(af[m], bfr[n], acc[m][n], 0, 0, 0);
        __syncthreads();
    }
    const int crow = by*128 + wr*64;
    const int ccol = bx*64 + wc*32 + (lane & 15);
#pragma unroll
    for (int m = 0; m < 4; ++m)
#pragma unroll
        for (int r = 0; r < 4; ++r) {
            int row = crow + m*16 + (lane>>4)*4 + r;
#pragma unroll
            for (int n = 0; n < 2; ++n)
                C[(size_t)row*N + ccol + n*16] = acc[m][n][r];
        }
}

// ---- decay attention: QBLK=128, dbuf prefetch, decay-reach jt skip ----
__global__ __launch_bounds__(256) void attn_kernel(
    const bf16* __restrict__ qh, const bf16* __restrict__ ql,
    const bf16* __restrict__ kh, const bf16* __restrict__ kl,
    const bf16* __restrict__ vt, const double* __restrict__ cl,
    const float* __restrict__ Gf, const float* __restrict__ rms_w,
    bf16* __restrict__ Y) {
    __shared__ __align__(16) bf16 Ksh[2][64*64];  // [key][d] swizzled, ping-pong
    __shared__ __align__(16) bf16 Ksl[2][64*64];
    __shared__ __align__(16) bf16 Vs[2][64*64];   // [d][key] swizzled, ping-pong
    __shared__ __align__(16) bf16 Ps[128*64];     // [qrow][key] swizzled
    const int rank = blockIdx.x >> 5, bh = blockIdx.x & 31;
    const int it = (rank < 8) ? (15 - rank) : (rank - 8);
    const int b = bh >> 4, h = bh & 15;
    const int tid = threadIdx.x, lane = tid & 63, wid = tid >> 6;
    const int i0 = it * 128;
    const int lr = lane & 15, lg4 = lane >> 4;
    // Q fragments: wave owns rows i0 + wid*32 .. +32 (2 m-frags)
    bf16x8 qfh[2][2], qfl[2][2];
#pragma unroll
    for (int mm = 0; mm < 2; ++mm) {
        int qtok = i0 + wid*32 + mm*16 + lr;
        size_t qa = (size_t)(b*T_ + qtok)*E_ + h*64 + lg4*8;
        qfh[mm][0] = *(const bf16x8*)(qh + qa);
        qfh[mm][1] = *(const bf16x8*)(qh + qa + 32);
        qfl[mm][0] = *(const bf16x8*)(ql + qa);
        qfl[mm][1] = *(const bf16x8*)(ql + qa + 32);
    }
    const double* clrow = cl + (size_t)bh*T_;
    const double base = clrow[i0];
    float cli2[2][4];
#pragma unroll
    for (int mm = 0; mm < 2; ++mm)
#pragma unroll
        for (int r = 0; r < 4; ++r)
            cli2[mm][r] = (float)(clrow[i0 + wid*32 + mm*16 + lg4*4 + r] - base);
    f32x4 oacc[2][4];
#pragma unroll
    for (int mm = 0; mm < 2; ++mm)
#pragma unroll
        for (int n = 0; n < 4; ++n) oacc[mm][n] = (f32x4)0.0f;
    const int srow8 = lane >> 3;                 // 0..7 within 8-row group
    const int csrc  = (lane & 7) ^ srow8;        // pre-swizzled source chunk
    auto STAGE = [&](int jt, int buf) {
        const int j0 = jt * 64;
#pragma unroll
        for (int i = 0; i < 2; ++i) {
            int krow = j0 + i*32 + wid*8 + srow8;
            int drow = i*32 + wid*8 + srow8;
            size_t gk = (size_t)(b*T_ + krow)*E_ + h*64 + csrc*8;
            gl_lds16(kh + gk, &Ksh[buf][(i*32 + wid*8)*64]);
            gl_lds16(kl + gk, &Ksl[buf][(i*32 + wid*8)*64]);
            gl_lds16(vt + (size_t)(bh*64 + drow)*T_ + j0 + csrc*8, &Vs[buf][(i*32 + wid*8)*64]);
        }
    };
    const int niter = 2*it + 2;
    // decay-reach skip: tiles with cl[i0] - cl[jend] < -95 give exp < bf16-subnormal
    // min -> exactly-zero P (bit-equivalent to computing them). cl monotone
    // decreasing -> threshold jt found by binary search.
    int jt_min;
    {
        int lo = 0, hi = niter - 1;             // hi (diagonal tile) always valid
        while (lo < hi) {
            int mid = (lo + hi) >> 1;
            int jend = mid*64 + 63; if (jend > i0) jend = i0;
            if (clrow[jend] <= base + 95.0) hi = mid; else lo = mid + 1;
        }
        jt_min = lo;
    }
    STAGE(jt_min, 0);
    __syncthreads();
    int cur = 0;
    for (int jt = jt_min; jt < niter; ++jt) {
        const int j0 = jt * 64;
        if (jt + 1 < niter) STAGE(jt + 1, cur ^ 1);   // prefetch overlaps compute
        // S = (qh+ql)(kh+kl)^T (3 products), decay+mask, write P (own rows)
#pragma unroll
        for (int n = 0; n < 4; ++n) {
            const int r = n*16 + lr;             // key row in tile
            const int sw = r & 7;
            const int ko = r*64;
            bf16x8 k_h0 = *(const bf16x8*)&Ksh[cur][ko + ((lg4 ^ sw)*8)];
            bf16x8 k_h1 = *(const bf16x8*)&Ksh[cur][ko + (((lg4+4) ^ sw)*8)];
            bf16x8 k_l0 = *(const bf16x8*)&Ksl[cur][ko + ((lg4 ^ sw)*8)];
            bf16x8 k_l1 = *(const bf16x8*)&Ksl[cur][ko + (((lg4+4) ^ sw)*8)];
            const int j = j0 + r;                // global key index
            const float cj = (float)(clrow[j] - base);
#pragma unroll
            for (int mm = 0; mm < 2; ++mm) {
                f32x4 s = (f32x4)0.0f;
                __builtin_amdgcn_s_setprio(1);
                s = __builtin_amdgcn_mfma_f32_16x16x32_bf16(qfl[mm][0], k_h0, s, 0, 0, 0);
                s = __builtin_amdgcn_mfma_f32_16x16x32_bf16(qfl[mm][1], k_h1, s, 0, 0, 0);
                s = __builtin_amdgcn_mfma_f32_16x16x32_bf16(qfh[mm][0], k_l0, s, 0, 0, 0);
                s = __builtin_amdgcn_mfma_f32_16x16x32_bf16(qfh[mm][1], k_l1, s, 0, 0, 0);
                s = __builtin_amdgcn_mfma_f32_16x16x32_bf16(qfh[mm][0], k_h0, s, 0, 0, 0);
                s = __builtin_amdgcn_mfma_f32_16x16x32_bf16(qfh[mm][1], k_h1, s, 0, 0, 0);
                __builtin_amdgcn_s_setprio(0);
                const int prbase = wid*32 + mm*16 + lg4*4;
#pragma unroll
                for (int r4 = 0; r4 < 4; ++r4) {
                    const int pr = prbase + r4;
                    const int qrow = i0 + pr;
                    float val = (j <= qrow)
                        ? s[r4] * __expf(cli2[mm][r4] - cj) : 0.0f;
                    const int cw = n*2 + (lr >> 3);
                    Ps[pr*64 + ((cw ^ (pr & 7))*8) + (lane & 7)] = (bf16)val;
                }
            }
        }
        // O += P V  (same-wave P round trip; lgkmcnt ordering suffices)
#pragma unroll
        for (int kk = 0; kk < 2; ++kk) {
            const int js = kk*4 + lg4;
            bf16x8 pf[2];
#pragma unroll
            for (int mm = 0; mm < 2; ++mm) {
                const int rp = wid*32 + mm*16 + lr;
                pf[mm] = *(const bf16x8*)&Ps[rp*64 + ((js ^ (rp & 7))*8)];
            }
            __builtin_amdgcn_s_setprio(1);
#pragma unroll
            for (int n = 0; n < 4; ++n) {
                const int rv = n*16 + lr;
                bf16x8 vf = *(const bf16x8*)&Vs[cur][rv*64 + ((js ^ (rv & 7))*8)];
                oacc[0][n] = __builtin_amdgcn_mfma_f32_16x16x32_bf16(pf[0], vf, oacc[0][n], 0, 0, 0);
                oacc[1][n] = __builtin_amdgcn_mfma_f32_16x16x32_bf16(pf[1], vf, oacc[1][n], 0, 0, 0);
            }
            __builtin_amdgcn_s_setprio(0);
        }
        __syncthreads();                         // drains prefetch vmcnt + Ps/Vs reads
        cur ^= 1;
    }
    // epilogue: RMSNorm over d=64, * rms_w, * pre-silu'd gate -> bf16 Y
#pragma unroll
    for (int mm = 0; mm < 2; ++mm)
#pragma unroll
        for (int r = 0; r < 4; ++r) {
            float ss = oacc[mm][0][r]*oacc[mm][0][r] + oacc[mm][1][r]*oacc[mm][1][r]
                     + oacc[mm][2][r]*oacc[mm][2][r] + oacc[mm][3][r]*oacc[mm][3][r];
#pragma unroll
            for (int off = 1; off < 16; off <<= 1) ss += __shfl_xor(ss, off, 64);
            const float scale = rsqrtf(ss * (1.0f/64.0f) + 1e-6f);
            const int gtok = b*T_ + i0 + wid*32 + mm*16 + lg4*4 + r;
#pragma unroll
            for (int n = 0; n < 4; ++n) {
                const int d = n*16 + lr;
                float o = oacc[mm][n][r] * scale * rms_w[d];
                float gate = Gf[(size_t)gtok*E_ + h*64 + d];
                Y[(size_t)gtok*E_ + h*64 + d] = (bf16)(o * gate);
            }
        }
}

extern "C" void kernel_launch(void* const* d_in, const int* in_sizes, int n_in,
                              void* d_out, int out_size, void* d_ws, size_t ws_size,
                              hipStream_t stream) {
    const float* x       = (const float*)d_in[0];
    const float* Wq      = (const float*)d_in[1];
    const float* Wk      = (const float*)d_in[2];
    const float* Wv      = (const float*)d_in[3];
    const float* Wa      = (const float*)d_in[4];
    const float* Wg      = (const float*)d_in[5];
    const float* Wo      = (const float*)d_in[6];
    const float* A_log   = (const float*)d_in[7];
    const float* dt_bias = (const float*)d_in[8];
    const float* rms_w   = (const float*)d_in[9];
    float* out = (float*)d_out;

    char* w = (char*)d_ws;
    size_t off = 0;
    auto alloc = [&](size_t bytes) {
        void* p = w + off; off += (bytes + 255) & ~(size_t)255; return p;
    };
    bf16*   xh   = (bf16*)  alloc((size_t)MTOK*E_*2);
    bf16*   xl   = (bf16*)  alloc((size_t)MTOK*E_*2);
    bf16*   WTqh = (bf16*)  alloc((size_t)2048*E_*2);
    bf16*   WTql = (bf16*)  alloc((size_t)2048*E_*2);
    bf16*   WTvg = (bf16*)  alloc((size_t)2048*E_*2);
    bf16*   WTo  = (bf16*)  alloc((size_t)E_*E_*2);
    bf16*   qhb  = (bf16*)  alloc((size_t)MTOK*E_*2);
    bf16*   qlb  = (bf16*)  alloc((size_t)MTOK*E_*2);
    bf16*   khb  = (bf16*)  alloc((size_t)MTOK*E_*2);
    bf16*   klb  = (bf16*)  alloc((size_t)MTOK*E_*2);
    bf16*   vt   = (bf16*)  alloc((size_t)MTOK*E_*2);
    float*  Gf   = (float*) alloc((size_t)MTOK*E_*4);
    float*  lg   = (float*) alloc((size_t)B_*H_*T_*4);
    double* cl   = (double*)alloc((size_t)B_*H_*T_*8);
    bf16*   Yb   = (bf16*)  alloc((size_t)MTOK*E_*2);
    float*  WaT  = (float*) alloc((size_t)H_*E_*4);

    hipLaunchKernelGGL(f2b_split_kernel, dim3(MTOK*E_/2048), dim3(256), 0, stream, x, xh, xl, MTOK*E_);
    hipLaunchKernelGGL(waT_kernel, dim3(64), dim3(256), 0, stream, Wa, WaT);
    hipLaunchKernelGGL(dt_kernel,  dim3(256), dim3(256), 0, stream, x, WaT, A_log, dt_bias, lg);
    hipLaunchKernelGGL(scan_kernel, dim3(B_*H_), dim3(256), 0, stream, lg, cl);

    // all weight transposes in one launch
    hipLaunchKernelGGL(prep_weights_kernel, dim3(5120), dim3(32, 8), 0, stream,
                       Wq, Wk, Wv, Wg, Wo, WTqh, WTql, WTvg, WTo);

    // fused projections
    hipLaunchKernelGGL(gemm_qk_kernel, dim3(512), dim3(256), 0, stream,
                       xh, xl, WTqh, WTql, qhb, qlb, khb, klb);
    hipLaunchKernelGGL(gemm_vg_kernel, dim3(512), dim3(256), 0, stream,
                       xh, WTvg, vt, Gf);

    // attention + RMSNorm + gate
    hipLaunchKernelGGL(attn_kernel, dim3(512), dim3(256), 0, stream,
                       qhb, qlb, khb, klb, vt, cl, Gf, rms_w, Yb);

    // output projection
    hipLaunchKernelGGL(gemm_out_kernel, dim3(512), dim3(256), 0, stream, Yb, WTo, out);
}

// Round 8
// 175.044 us; speedup vs baseline: 2.9267x; 1.0321x over previous
//
#include <hip/hip_runtime.h>
#include <hip/hip_bf16.h>
#include <math.h>

#define B_ 2
#define T_ 2048
#define E_ 1024
#define H_ 16
#define D_ 64
#define MTOK (B_*T_)   // 4096

typedef __bf16 bf16;
typedef __bf16 bf16x8 __attribute__((ext_vector_type(8)));
typedef __bf16 bf16x4 __attribute__((ext_vector_type(4)));
typedef float  f32x4  __attribute__((ext_vector_type(4)));

__device__ __forceinline__ void gl_lds16(const void* g, void* l) {
    __builtin_amdgcn_global_load_lds(
        (const __attribute__((address_space(1))) void*)g,
        (__attribute__((address_space(3))) void*)l, 16, 0, 0);
}

// ---- all weight transposes in ONE launch: seg 0,1 split (Wq,Wk); 2,3,4 plain ----
__global__ void prep_weights_kernel(const float* __restrict__ Wq, const float* __restrict__ Wk,
                                    const float* __restrict__ Wv, const float* __restrict__ Wg,
                                    const float* __restrict__ Wo,
                                    bf16* __restrict__ WTqh, bf16* __restrict__ WTql,
                                    bf16* __restrict__ WTvg, bf16* __restrict__ WTo) {
    __shared__ float t[32][33];
    const int seg = blockIdx.x >> 10;            // 5 segments x 1024 blocks
    const int bid = blockIdx.x & 1023;
    const float* src = (seg == 0) ? Wq : (seg == 1) ? Wk : (seg == 2) ? Wv
                     : (seg == 3) ? Wg : Wo;
    const int bx = bid & 31, by = bid >> 5;
    const int tx = threadIdx.x, ty = threadIdx.y;
#pragma unroll
    for (int i = ty; i < 32; i += 8)
        t[i][tx] = src[(size_t)(by*32 + i)*1024 + bx*32 + tx];
    __syncthreads();
    if (seg < 2) {
        bf16* dh = WTqh + (size_t)seg*1024*1024;
        bf16* dl = WTql + (size_t)seg*1024*1024;
#pragma unroll
        for (int i = ty; i < 32; i += 8) {
            float v = t[tx][i];
            bf16 h = (bf16)v;
            size_t idx = (size_t)(bx*32 + i)*1024 + by*32 + tx;
            dh[idx] = h;
            dl[idx] = (bf16)(v - (float)h);
        }
    } else {
        bf16* dst = (seg == 2) ? WTvg : (seg == 3) ? (WTvg + (size_t)1024*1024) : WTo;
#pragma unroll
        for (int i = ty; i < 32; i += 8)
            dst[(size_t)(bx*32 + i)*1024 + by*32 + tx] = (bf16)t[tx][i];
    }
}

// ---------------- Wa [1024][16] f32 -> WaT [16][1024] f32 ----------------
__global__ __launch_bounds__(256) void waT_kernel(const float* __restrict__ Wa,
                                                  float* __restrict__ WaT) {
    int idx = blockIdx.x * 256 + threadIdx.x;    // grid 64 -> 16384
    int h = idx >> 10, k = idx & 1023;
    WaT[idx] = Wa[k*H_ + h];
}

// ---- dt -> log(alpha+1e-8) AND x -> xh/xl split (x staged once in LDS) ----
__global__ __launch_bounds__(256) void dtx_kernel(const float* __restrict__ x,
                                                  const float* __restrict__ WaT,
                                                  const float* __restrict__ A_log,
                                                  const float* __restrict__ dt_bias,
                                                  float* __restrict__ lg,
                                                  bf16* __restrict__ xh,
                                                  bf16* __restrict__ xl) {
    __shared__ float xs[16][1032];               // pad 8
    const int tb = blockIdx.x * 16;              // grid 256
    const int tid = threadIdx.x;
#pragma unroll
    for (int v = tid; v < 2048; v += 256) {      // 16 rows x 128 chunks-of-8
        int row = v >> 7, c8 = (v & 127) * 8;
        const float* src = x + (size_t)(tb + row)*E_ + c8;
        float4 a = *(const float4*)src;
        float4 b = *(const float4*)(src + 4);
        float va[8] = {a.x, a.y, a.z, a.w, b.x, b.y, b.z, b.w};
        bf16x8 hv, lv;
#pragma unroll
        for (int j = 0; j < 8; ++j) {
            xs[row][c8+j] = va[j];
            bf16 h = (bf16)va[j];
            hv[j] = h;
            lv[j] = (bf16)(va[j] - (float)h);
        }
        *(bf16x8*)(xh + (size_t)(tb + row)*E_ + c8) = hv;
        *(bf16x8*)(xl + (size_t)(tb + row)*E_ + c8) = lv;
    }
    __syncthreads();
    const int i = tid >> 4, h = tid & 15;
    const float* wrow = WaT + (size_t)h*1024;
    float acc = 0.f;
#pragma unroll 8
    for (int k = 0; k < 1024; k += 4) {
        float4 xv = *(const float4*)&xs[i][k];
        float4 wv = *(const float4*)(wrow + k);
        acc += xv.x*wv.x + xv.y*wv.y + xv.z*wv.z + xv.w*wv.w;
    }
    float z   = acc + dt_bias[h];
    float dtv = (z > 20.f) ? z : log1pf(expf(z));
    float la  = -expf(A_log[h]) * dtv;
    float l   = logf(expf(la) + 1e-8f);
    int n = tb + i;
    int b = n / T_, t = n % T_;
    lg[(size_t)(b*H_ + h)*T_ + t] = l;
}

// ---------------- f64 inclusive scan of lg rows -> cl ----------------
__global__ __launch_bounds__(256) void scan_kernel(const float* __restrict__ lg,
                                                   double* __restrict__ cl) {
    int row = blockIdx.x, tid = threadIdx.x;
    __shared__ double ls[256];
    const float* p = lg + (size_t)row*T_ + tid*8;
    double loc[8], s = 0.0;
#pragma unroll
    for (int j = 0; j < 8; ++j) { s += (double)p[j]; loc[j] = s; }
    ls[tid] = s;
    __syncthreads();
    for (int off = 1; off < 256; off <<= 1) {
        double add = (tid >= off) ? ls[tid - off] : 0.0;
        __syncthreads();
        ls[tid] += add;
        __syncthreads();
    }
    double prefix = ls[tid] - s;
    double* o = cl + (size_t)row*T_ + tid*8;
#pragma unroll
    for (int j = 0; j < 8; ++j) o[j] = prefix + loc[j];
}

// ==== merged projection GEMMs: blocks 0-511 = split Q|K, 512-1023 = plain V|G ====
// LDS tiles chunk-XOR swizzled (chunk' = chunk ^ ((row>>1)&3)): linear gl_lds16
// dest + pre-swizzled global source + swizzled ds_read -> 2-way (free) banks.
__global__ __launch_bounds__(256) void gemm_qkvg_kernel(
    const bf16* __restrict__ Ah, const bf16* __restrict__ Al,
    const bf16* __restrict__ Bh, const bf16* __restrict__ Bl,
    const bf16* __restrict__ BTvg,
    bf16* __restrict__ qhb, bf16* __restrict__ qlb,
    bf16* __restrict__ khb, bf16* __restrict__ klb,
    bf16* __restrict__ vt, float* __restrict__ Gf) {
    const int K = E_;
    __shared__ __align__(16) bf16 S[4][128*32];
    const int tid = threadIdx.x, lane = tid & 63, wid = tid >> 6;
    const int wr = wid >> 1, wc = wid & 1;
    const int lr = lane & 15, lg4 = lane >> 4;
    const int tr = tid >> 2;
    const int tc = ((tid & 3) ^ ((tid >> 3) & 3)) * 8;   // pre-swizzled src chunk
    const int co = (lg4 ^ ((lr >> 1) & 3)) * 8;          // swizzled read chunk
    if (blockIdx.x < 512) {
        // ---------------- split GEMM (Q|K) + L2-norm + hi/lo epilogue ----------------
        int bid = blockIdx.x;
        bid = (bid & 7) * 64 + (bid >> 3);               // XCD swizzle
        const int bx = bid & 15, by = bid >> 4;          // nbx = 2048/128
        f32x4 acc[4][4];
#pragma unroll
        for (int m = 0; m < 4; ++m)
#pragma unroll
            for (int n = 0; n < 4; ++n) acc[m][n] = (f32x4)0.0f;
        for (int k0 = 0; k0 < K; k0 += 32) {
#pragma unroll
            for (int i = 0; i < 2; ++i) {
                size_t ga = (size_t)(by*128 + i*64 + tr)*K + k0 + tc;
                size_t gb = (size_t)(bx*128 + i*64 + tr)*K + k0 + tc;
                gl_lds16(Ah + ga, &S[0][(i*256 + wid*64)*8]);
                gl_lds16(Al + ga, &S[1][(i*256 + wid*64)*8]);
                gl_lds16(Bh + gb, &S[2][(i*256 + wid*64)*8]);
                gl_lds16(Bl + gb, &S[3][(i*256 + wid*64)*8]);
            }
            __syncthreads();
            bf16x8 ah[4], al[4], bh[4], bl[4];
#pragma unroll
            for (int m = 0; m < 4; ++m) {
                int o = (wr*64 + m*16 + lr)*32 + co;
                ah[m] = *(const bf16x8*)&S[0][o];
                al[m] = *(const bf16x8*)&S[1][o];
            }
#pragma unroll
            for (int n = 0; n < 4; ++n) {
                int o = (wc*64 + n*16 + lr)*32 + co;
                bh[n] = *(const bf16x8*)&S[2][o];
                bl[n] = *(const bf16x8*)&S[3][o];
            }
#pragma unroll
            for (int m = 0; m < 4; ++m)
#pragma unroll
                for (int n = 0; n < 4; ++n) {
                    acc[m][n] = __builtin_amdgcn_mfma_f32_16x16x32_bf16(al[m], bh[n], acc[m][n], 0, 0, 0);
                    acc[m][n] = __builtin_amdgcn_mfma_f32_16x16x32_bf16(ah[m], bl[n], acc[m][n], 0, 0, 0);
                    acc[m][n] = __builtin_amdgcn_mfma_f32_16x16x32_bf16(ah[m], bh[n], acc[m][n], 0, 0, 0);
                }
            __syncthreads();
        }
        const int headg = bx*2 + wc;                     // 0..31
        bf16* dh = (headg < 16) ? qhb : khb;
        bf16* dl = (headg < 16) ? qlb : klb;
        const int h = headg & 15;
#pragma unroll
        for (int m = 0; m < 4; ++m)
#pragma unroll
            for (int r = 0; r < 4; ++r) {
                float ss = acc[m][0][r]*acc[m][0][r] + acc[m][1][r]*acc[m][1][r]
                         + acc[m][2][r]*acc[m][2][r] + acc[m][3][r]*acc[m][3][r];
#pragma unroll
                for (int off = 1; off < 16; off <<= 1) ss += __shfl_xor(ss, off, 64);
                float sc = 1.0f / fmaxf(sqrtf(ss), 1e-12f);
                int token = by*128 + wr*64 + m*16 + lg4*4 + r;
#pragma unroll
                for (int n = 0; n < 4; ++n) {
                    int d = n*16 + lr;
                    float qv = acc[m][n][r] * sc;
                    bf16 hv = (bf16)qv;
                    size_t idx = ((size_t)token*H_ + h)*64 + d;
                    dh[idx] = hv;
                    dl[idx] = (bf16)(qv - (float)hv);
                }
            }
    } else {
        // ---------------- plain GEMM (V|G) + transposed-V / silu-G epilogue ----------------
        int bid = blockIdx.x - 512;
        bid = (bid & 7) * 64 + (bid >> 3);               // XCD swizzle
        const int bx = bid & 15, by = bid >> 4;
        f32x4 acc[4][4];
#pragma unroll
        for (int m = 0; m < 4; ++m)
#pragma unroll
            for (int n = 0; n < 4; ++n) acc[m][n] = (f32x4)0.0f;
        for (int k0 = 0; k0 < K; k0 += 32) {
#pragma unroll
            for (int i = 0; i < 2; ++i) {
                gl_lds16(Ah   + (size_t)(by*128 + i*64 + tr)*K + k0 + tc, &S[0][(i*256 + wid*64)*8]);
                gl_lds16(BTvg + (size_t)(bx*128 + i*64 + tr)*K + k0 + tc, &S[1][(i*256 + wid*64)*8]);
            }
            __syncthreads();
            bf16x8 af[4], bfr[4];
#pragma unroll
            for (int m = 0; m < 4; ++m)
                af[m] = *(const bf16x8*)&S[0][(wr*64 + m*16 + lr)*32 + co];
#pragma unroll
            for (int n = 0; n < 4; ++n)
                bfr[n] = *(const bf16x8*)&S[1][(wc*64 + n*16 + lr)*32 + co];
#pragma unroll
            for (int m = 0; m < 4; ++m)
#pragma unroll
                for (int n = 0; n < 4; ++n)
                    acc[m][n] = __builtin_amdgcn_mfma_f32_16x16x32_bf16(af[m], bfr[n], acc[m][n], 0, 0, 0);
            __syncthreads();
        }
        const int colbase = bx*128 + wc*64;
        const int b = by >> 4;
        if (colbase < 1024) {
            const int head = colbase >> 6;
#pragma unroll
            for (int m = 0; m < 4; ++m) {
                int trow = by*128 + wr*64 + m*16 + lg4*4;
                int tloc = trow - b*T_;
#pragma unroll
                for (int n = 0; n < 4; ++n) {
                    int d = n*16 + lr;
                    bf16x4 pk;
                    pk[0] = (bf16)acc[m][n][0]; pk[1] = (bf16)acc[m][n][1];
                    pk[2] = (bf16)acc[m][n][2]; pk[3] = (bf16)acc[m][n][3];
                    *(bf16x4*)(vt + ((size_t)((b*H_ + head)*64 + d))*T_ + tloc) = pk;
                }
            }
        } else {
#pragma unroll
            for (int m = 0; m < 4; ++m)
#pragma unroll
                for (int r = 0; r < 4; ++r) {
                    int token = by*128 + wr*64 + m*16 + lg4*4 + r;
#pragma unroll
                    for (int n = 0; n < 4; ++n) {
                        int colg = colbase - 1024 + n*16 + lr;
                        float g = acc[m][n][r];
                        Gf[(size_t)token*E_ + colg] = g / (1.0f + __expf(-g));
                    }
                }
        }
    }
}

// ---- output GEMM: out f32 = Yb bf16 @ WoT, 128x64 tile, swizzled LDS ----
__global__ __launch_bounds__(256) void gemm_out_kernel(
    const bf16* __restrict__ A, const bf16* __restrict__ BT, float* __restrict__ C) {
    const int K = E_, N = E_;
    __shared__ __align__(16) bf16 As[128*32];
    __shared__ __align__(16) bf16 Bs[64*32];
    int bid = blockIdx.x;
    bid = (bid & 7) * 64 + (bid >> 3);           // XCD swizzle, 512 blocks
    const int bx = bid & 15, by = bid >> 4;      // nbx = 1024/64 = 16
    const int tid = threadIdx.x, lane = tid & 63, wid = tid >> 6;
    const int wr = wid >> 1, wc = wid & 1;       // waves 64x32
    const int lr = lane & 15, lg4 = lane >> 4;
    f32x4 acc[4][2];
#pragma unroll
    for (int m = 0; m < 4; ++m)
#pragma unroll
        for (int n = 0; n < 2; ++n) acc[m][n] = (f32x4)0.0f;
    const int tr = tid >> 2;
    const int tc = ((tid & 3) ^ ((tid >> 3) & 3)) * 8;
    const int co = (lg4 ^ ((lr >> 1) & 3)) * 8;
    for (int k0 = 0; k0 < K; k0 += 32) {
#pragma unroll
        for (int i = 0; i < 2; ++i)
            gl_lds16(A + (size_t)(by*128 + i*64 + tr)*K + k0 + tc, &As[(i*256 + wid*64)*8]);
        gl_lds16(BT + (size_t)(bx*64 + tr)*K + k0 + tc, &Bs[(wid*64)*8]);
        __syncthreads();
        bf16x8 af[4], bfr[2];
#pragma unroll
        for (int m = 0; m < 4; ++m)
            af[m] = *(const bf16x8*)&As[(wr*64 + m*16 + lr)*32 + co];
#pragma unroll
        for (int n = 0; n < 2; ++n)
            bfr[n] = *(const bf16x8*)&Bs[(wc*32 + n*16 + lr)*32 + co];
#pragma unroll
        for (int m = 0; m < 4; ++m)
#pragma unroll
            for (int n = 0; n < 2; ++n)
                acc[m][n] = __builtin_amdgcn_mfma_f32_16x16x32_bf16(af[m], bfr[n], acc[m][n], 0, 0, 0);
        __syncthreads();
    }
    const int crow = by*128 + wr*64;
    const int ccol = bx*64 + wc*32 + lr;
#pragma unroll
    for (int m = 0; m < 4; ++m)
#pragma unroll
        for (int r = 0; r < 4; ++r) {
            int row = crow + m*16 + lg4*4 + r;
#pragma unroll
            for (int n = 0; n < 2; ++n)
                C[(size_t)row*N + ccol + n*16] = acc[m][n][r];
        }
}

// ---- decay attention: QBLK=128, dbuf prefetch, decay-reach jt skip ----
__global__ __launch_bounds__(256) void attn_kernel(
    const bf16* __restrict__ qh, const bf16* __restrict__ ql,
    const bf16* __restrict__ kh, const bf16* __restrict__ kl,
    const bf16* __restrict__ vt, const double* __restrict__ cl,
    const float* __restrict__ Gf, const float* __restrict__ rms_w,
    bf16* __restrict__ Y) {
    __shared__ __align__(16) bf16 Ksh[2][64*64];  // [key][d] swizzled, ping-pong
    __shared__ __align__(16) bf16 Ksl[2][64*64];
    __shared__ __align__(16) bf16 Vs[2][64*64];   // [d][key] swizzled, ping-pong
    __shared__ __align__(16) bf16 Ps[128*64];     // [qrow][key] swizzled
    const int rank = blockIdx.x >> 5, bh = blockIdx.x & 31;
    const int it = (rank < 8) ? (15 - rank) : (rank - 8);
    const int b = bh >> 4, h = bh & 15;
    const int tid = threadIdx.x, lane = tid & 63, wid = tid >> 6;
    const int i0 = it * 128;
    const int lr = lane & 15, lg4 = lane >> 4;
    bf16x8 qfh[2][2], qfl[2][2];
#pragma unroll
    for (int mm = 0; mm < 2; ++mm) {
        int qtok = i0 + wid*32 + mm*16 + lr;
        size_t qa = (size_t)(b*T_ + qtok)*E_ + h*64 + lg4*8;
        qfh[mm][0] = *(const bf16x8*)(qh + qa);
        qfh[mm][1] = *(const bf16x8*)(qh + qa + 32);
        qfl[mm][0] = *(const bf16x8*)(ql + qa);
        qfl[mm][1] = *(const bf16x8*)(ql + qa + 32);
    }
    const double* clrow = cl + (size_t)bh*T_;
    const double base = clrow[i0];
    float cli2[2][4];
#pragma unroll
    for (int mm = 0; mm < 2; ++mm)
#pragma unroll
        for (int r = 0; r < 4; ++r)
            cli2[mm][r] = (float)(clrow[i0 + wid*32 + mm*16 + lg4*4 + r] - base);
    f32x4 oacc[2][4];
#pragma unroll
    for (int mm = 0; mm < 2; ++mm)
#pragma unroll
        for (int n = 0; n < 4; ++n) oacc[mm][n] = (f32x4)0.0f;
    const int srow8 = lane >> 3;
    const int csrc  = (lane & 7) ^ srow8;
    auto STAGE = [&](int jt, int buf) {
        const int j0 = jt * 64;
#pragma unroll
        for (int i = 0; i < 2; ++i) {
            int krow = j0 + i*32 + wid*8 + srow8;
            int drow = i*32 + wid*8 + srow8;
            size_t gk = (size_t)(b*T_ + krow)*E_ + h*64 + csrc*8;
            gl_lds16(kh + gk, &Ksh[buf][(i*32 + wid*8)*64]);
            gl_lds16(kl + gk, &Ksl[buf][(i*32 + wid*8)*64]);
            gl_lds16(vt + (size_t)(bh*64 + drow)*T_ + j0 + csrc*8, &Vs[buf][(i*32 + wid*8)*64]);
        }
    };
    const int niter = 2*it + 2;
    int jt_min;
    {
        int lo = 0, hi = niter - 1;
        while (lo < hi) {
            int mid = (lo + hi) >> 1;
            int jend = mid*64 + 63; if (jend > i0) jend = i0;
            if (clrow[jend] <= base + 95.0) hi = mid; else lo = mid + 1;
        }
        jt_min = lo;
    }
    STAGE(jt_min, 0);
    __syncthreads();
    int cur = 0;
    for (int jt = jt_min; jt < niter; ++jt) {
        const int j0 = jt * 64;
        if (jt + 1 < niter) STAGE(jt + 1, cur ^ 1);
#pragma unroll
        for (int n = 0; n < 4; ++n) {
            const int r = n*16 + lr;
            const int sw = r & 7;
            const int ko = r*64;
            bf16x8 k_h0 = *(const bf16x8*)&Ksh[cur][ko + ((lg4 ^ sw)*8)];
            bf16x8 k_h1 = *(const bf16x8*)&Ksh[cur][ko + (((lg4+4) ^ sw)*8)];
            bf16x8 k_l0 = *(const bf16x8*)&Ksl[cur][ko + ((lg4 ^ sw)*8)];
            bf16x8 k_l1 = *(const bf16x8*)&Ksl[cur][ko + (((lg4+4) ^ sw)*8)];
            const int j = j0 + r;
            const float cj = (float)(clrow[j] - base);
#pragma unroll
            for (int mm = 0; mm < 2; ++mm) {
                f32x4 s = (f32x4)0.0f;
                __builtin_amdgcn_s_setprio(1);
                s = __builtin_amdgcn_mfma_f32_16x16x32_bf16(qfl[mm][0], k_h0, s, 0, 0, 0);
                s = __builtin_amdgcn_mfma_f32_16x16x32_bf16(qfl[mm][1], k_h1, s, 0, 0, 0);
                s = __builtin_amdgcn_mfma_f32_16x16x32_bf16(qfh[mm][0], k_l0, s, 0, 0, 0);
                s = __builtin_amdgcn_mfma_f32_16x16x32_bf16(qfh[mm][1], k_l1, s, 0, 0, 0);
                s = __builtin_amdgcn_mfma_f32_16x16x32_bf16(qfh[mm][0], k_h0, s, 0, 0, 0);
                s = __builtin_amdgcn_mfma_f32_16x16x32_bf16(qfh[mm][1], k_h1, s, 0, 0, 0);
                __builtin_amdgcn_s_setprio(0);
                const int prbase = wid*32 + mm*16 + lg4*4;
#pragma unroll
                for (int r4 = 0; r4 < 4; ++r4) {
                    const int pr = prbase + r4;
                    const int qrow = i0 + pr;
                    float val = (j <= qrow)
                        ? s[r4] * __expf(cli2[mm][r4] - cj) : 0.0f;
                    const int cw = n*2 + (lr >> 3);
                    Ps[pr*64 + ((cw ^ (pr & 7))*8) + (lane & 7)] = (bf16)val;
                }
            }
        }
#pragma unroll
        for (int kk = 0; kk < 2; ++kk) {
            const int js = kk*4 + lg4;
            bf16x8 pf[2];
#pragma unroll
            for (int mm = 0; mm < 2; ++mm) {
                const int rp = wid*32 + mm*16 + lr;
                pf[mm] = *(const bf16x8*)&Ps[rp*64 + ((js ^ (rp & 7))*8)];
            }
            __builtin_amdgcn_s_setprio(1);
#pragma unroll
            for (int n = 0; n < 4; ++n) {
                const int rv = n*16 + lr;
                bf16x8 vf = *(const bf16x8*)&Vs[cur][rv*64 + ((js ^ (rv & 7))*8)];
                oacc[0][n] = __builtin_amdgcn_mfma_f32_16x16x32_bf16(pf[0], vf, oacc[0][n], 0, 0, 0);
                oacc[1][n] = __builtin_amdgcn_mfma_f32_16x16x32_bf16(pf[1], vf, oacc[1][n], 0, 0, 0);
            }
            __builtin_amdgcn_s_setprio(0);
        }
        __syncthreads();
        cur ^= 1;
    }
#pragma unroll
    for (int mm = 0; mm < 2; ++mm)
#pragma unroll
        for (int r = 0; r < 4; ++r) {
            float ss = oacc[mm][0][r]*oacc[mm][0][r] + oacc[mm][1][r]*oacc[mm][1][r]
                     + oacc[mm][2][r]*oacc[mm][2][r] + oacc[mm][3][r]*oacc[mm][3][r];
#pragma unroll
            for (int off = 1; off < 16; off <<= 1) ss += __shfl_xor(ss, off, 64);
            const float scale = rsqrtf(ss * (1.0f/64.0f) + 1e-6f);
            const int gtok = b*T_ + i0 + wid*32 + mm*16 + lg4*4 + r;
#pragma unroll
            for (int n = 0; n < 4; ++n) {
                const int d = n*16 + lr;
                float o = oacc[mm][n][r] * scale * rms_w[d];
                float gate = Gf[(size_t)gtok*E_ + h*64 + d];
                Y[(size_t)gtok*E_ + h*64 + d] = (bf16)(o * gate);
            }
        }
}

extern "C" void kernel_launch(void* const* d_in, const int* in_sizes, int n_in,
                              void* d_out, int out_size, void* d_ws, size_t ws_size,
                              hipStream_t stream) {
    const float* x       = (const float*)d_in[0];
    const float* Wq      = (const float*)d_in[1];
    const float* Wk      = (const float*)d_in[2];
    const float* Wv      = (const float*)d_in[3];
    const float* Wa      = (const float*)d_in[4];
    const float* Wg      = (const float*)d_in[5];
    const float* Wo      = (const float*)d_in[6];
    const float* A_log   = (const float*)d_in[7];
    const float* dt_bias = (const float*)d_in[8];
    const float* rms_w   = (const float*)d_in[9];
    float* out = (float*)d_out;

    char* w = (char*)d_ws;
    size_t off = 0;
    auto alloc = [&](size_t bytes) {
        void* p = w + off; off += (bytes + 255) & ~(size_t)255; return p;
    };
    bf16*   xh   = (bf16*)  alloc((size_t)MTOK*E_*2);
    bf16*   xl   = (bf16*)  alloc((size_t)MTOK*E_*2);
    bf16*   WTqh = (bf16*)  alloc((size_t)2048*E_*2);
    bf16*   WTql = (bf16*)  alloc((size_t)2048*E_*2);
    bf16*   WTvg = (bf16*)  alloc((size_t)2048*E_*2);
    bf16*   WTo  = (bf16*)  alloc((size_t)E_*E_*2);
    bf16*   qhb  = (bf16*)  alloc((size_t)MTOK*E_*2);
    bf16*   qlb  = (bf16*)  alloc((size_t)MTOK*E_*2);
    bf16*   khb  = (bf16*)  alloc((size_t)MTOK*E_*2);
    bf16*   klb  = (bf16*)  alloc((size_t)MTOK*E_*2);
    bf16*   vt   = (bf16*)  alloc((size_t)MTOK*E_*2);
    float*  Gf   = (float*) alloc((size_t)MTOK*E_*4);
    float*  lg   = (float*) alloc((size_t)B_*H_*T_*4);
    double* cl   = (double*)alloc((size_t)B_*H_*T_*8);
    bf16*   Yb   = (bf16*)  alloc((size_t)MTOK*E_*2);
    float*  WaT  = (float*) alloc((size_t)H_*E_*4);

    hipLaunchKernelGGL(waT_kernel, dim3(64), dim3(256), 0, stream, Wa, WaT);
    hipLaunchKernelGGL(dtx_kernel, dim3(256), dim3(256), 0, stream,
                       x, WaT, A_log, dt_bias, lg, xh, xl);
    hipLaunchKernelGGL(scan_kernel, dim3(B_*H_), dim3(256), 0, stream, lg, cl);

    // all weight transposes in one launch
    hipLaunchKernelGGL(prep_weights_kernel, dim3(5120), dim3(32, 8), 0, stream,
                       Wq, Wk, Wv, Wg, Wo, WTqh, WTql, WTvg, WTo);

    // merged projection GEMMs (Q|K split first = LPT, then V|G backfills the tail)
    hipLaunchKernelGGL(gemm_qkvg_kernel, dim3(1024), dim3(256), 0, stream,
                       xh, xl, WTqh, WTql, WTvg, qhb, qlb, khb, klb, vt, Gf);

    // attention + RMSNorm + gate
    hipLaunchKernelGGL(attn_kernel, dim3(512), dim3(256), 0, stream,
                       qhb, qlb, khb, klb, vt, cl, Gf, rms_w, Yb);

    // output projection
    hipLaunchKernelGGL(gemm_out_kernel, dim3(512), dim3(256), 0, stream, Yb, WTo, out);
}

// Round 9
// 159.340 us; speedup vs baseline: 3.2151x; 1.0986x over previous
//
#include <hip/hip_runtime.h>
#include <hip/hip_bf16.h>
#include <math.h>

#define B_ 2
#define T_ 2048
#define E_ 1024
#define H_ 16
#define D_ 64
#define MTOK (B_*T_)   // 4096

typedef __bf16 bf16;
typedef __bf16 bf16x8 __attribute__((ext_vector_type(8)));
typedef __bf16 bf16x4 __attribute__((ext_vector_type(4)));
typedef float  f32x4  __attribute__((ext_vector_type(4)));

__device__ __forceinline__ void gl_lds16(const void* g, void* l) {
    __builtin_amdgcn_global_load_lds(
        (const __attribute__((address_space(1))) void*)g,
        (__attribute__((address_space(3))) void*)l, 16, 0, 0);
}

// ---- all weight transposes in ONE launch: seg 0,1 split (Wq,Wk); 2,3,4 plain; 5 WaT ----
__global__ void prep_weights_kernel(const float* __restrict__ Wq, const float* __restrict__ Wk,
                                    const float* __restrict__ Wv, const float* __restrict__ Wg,
                                    const float* __restrict__ Wo, const float* __restrict__ Wa,
                                    bf16* __restrict__ WTqh, bf16* __restrict__ WTql,
                                    bf16* __restrict__ WTvg, bf16* __restrict__ WTo,
                                    float* __restrict__ WaT) {
    const int tx = threadIdx.x, ty = threadIdx.y;
    if (blockIdx.x >= 5120) {                    // seg 5: Wa [1024][16] -> WaT [16][1024]
        int idx = (blockIdx.x - 5120) * 256 + ty*32 + tx;
        int h = idx >> 10, k = idx & 1023;
        WaT[idx] = Wa[k*H_ + h];
        return;
    }
    __shared__ float t[32][33];
    const int seg = blockIdx.x >> 10;            // 5 segments x 1024 blocks
    const int bid = blockIdx.x & 1023;
    const float* src = (seg == 0) ? Wq : (seg == 1) ? Wk : (seg == 2) ? Wv
                     : (seg == 3) ? Wg : Wo;
    const int bx = bid & 31, by = bid >> 5;
#pragma unroll
    for (int i = ty; i < 32; i += 8)
        t[i][tx] = src[(size_t)(by*32 + i)*1024 + bx*32 + tx];
    __syncthreads();
    if (seg < 2) {
        bf16* dh = WTqh + (size_t)seg*1024*1024;
        bf16* dl = WTql + (size_t)seg*1024*1024;
#pragma unroll
        for (int i = ty; i < 32; i += 8) {
            float v = t[tx][i];
            bf16 h = (bf16)v;
            size_t idx = (size_t)(bx*32 + i)*1024 + by*32 + tx;
            dh[idx] = h;
            dl[idx] = (bf16)(v - (float)h);
        }
    } else {
        bf16* dst = (seg == 2) ? WTvg : (seg == 3) ? (WTvg + (size_t)1024*1024) : WTo;
#pragma unroll
        for (int i = ty; i < 32; i += 8)
            dst[(size_t)(bx*32 + i)*1024 + by*32 + tx] = (bf16)t[tx][i];
    }
}

// ---- dt -> log(alpha+1e-8) AND x -> xh/xl split (x staged once in LDS) ----
__global__ __launch_bounds__(256) void dtx_kernel(const float* __restrict__ x,
                                                  const float* __restrict__ WaT,
                                                  const float* __restrict__ A_log,
                                                  const float* __restrict__ dt_bias,
                                                  float* __restrict__ lg,
                                                  bf16* __restrict__ xh,
                                                  bf16* __restrict__ xl) {
    __shared__ float xs[16][1032];               // pad 8
    const int tb = blockIdx.x * 16;              // grid 256
    const int tid = threadIdx.x;
#pragma unroll
    for (int v = tid; v < 2048; v += 256) {      // 16 rows x 128 chunks-of-8
        int row = v >> 7, c8 = (v & 127) * 8;
        const float* src = x + (size_t)(tb + row)*E_ + c8;
        float4 a = *(const float4*)src;
        float4 b = *(const float4*)(src + 4);
        float va[8] = {a.x, a.y, a.z, a.w, b.x, b.y, b.z, b.w};
        bf16x8 hv, lv;
#pragma unroll
        for (int j = 0; j < 8; ++j) {
            xs[row][c8+j] = va[j];
            bf16 h = (bf16)va[j];
            hv[j] = h;
            lv[j] = (bf16)(va[j] - (float)h);
        }
        *(bf16x8*)(xh + (size_t)(tb + row)*E_ + c8) = hv;
        *(bf16x8*)(xl + (size_t)(tb + row)*E_ + c8) = lv;
    }
    __syncthreads();
    const int i = tid >> 4, h = tid & 15;
    const float* wrow = WaT + (size_t)h*1024;
    float acc = 0.f;
#pragma unroll 8
    for (int k = 0; k < 1024; k += 4) {
        float4 xv = *(const float4*)&xs[i][k];
        float4 wv = *(const float4*)(wrow + k);
        acc += xv.x*wv.x + xv.y*wv.y + xv.z*wv.z + xv.w*wv.w;
    }
    float z   = acc + dt_bias[h];
    float dtv = (z > 20.f) ? z : log1pf(expf(z));
    float la  = -expf(A_log[h]) * dtv;
    float l   = logf(expf(la) + 1e-8f);
    int n = tb + i;
    int b = n / T_, t = n % T_;
    lg[(size_t)(b*H_ + h)*T_ + t] = l;
}

// ---------------- f64 inclusive scan of lg rows -> cl ----------------
__global__ __launch_bounds__(256) void scan_kernel(const float* __restrict__ lg,
                                                   double* __restrict__ cl) {
    int row = blockIdx.x, tid = threadIdx.x;
    __shared__ double ls[256];
    const float* p = lg + (size_t)row*T_ + tid*8;
    double loc[8], s = 0.0;
#pragma unroll
    for (int j = 0; j < 8; ++j) { s += (double)p[j]; loc[j] = s; }
    ls[tid] = s;
    __syncthreads();
    for (int off = 1; off < 256; off <<= 1) {
        double add = (tid >= off) ? ls[tid - off] : 0.0;
        __syncthreads();
        ls[tid] += add;
        __syncthreads();
    }
    double prefix = ls[tid] - s;
    double* o = cl + (size_t)row*T_ + tid*8;
#pragma unroll
    for (int j = 0; j < 8; ++j) o[j] = prefix + loc[j];
}

// ==== fused projection GEMM: each block does the (by,bx) tile of BOTH the
// split Q|K GEMM (3-product) and the plain V|G GEMM, sharing staged A tiles
// and A fragments. Homogeneous blocks -> perfect balance. Swizzled LDS. ====
__global__ __launch_bounds__(256, 2) void gemm_qkvg_kernel(
    const bf16* __restrict__ Ah, const bf16* __restrict__ Al,
    const bf16* __restrict__ Bh, const bf16* __restrict__ Bl,
    const bf16* __restrict__ BTvg,
    bf16* __restrict__ qhb, bf16* __restrict__ qlb,
    bf16* __restrict__ khb, bf16* __restrict__ klb,
    bf16* __restrict__ vt, float* __restrict__ Gf) {
    const int K = E_;
    __shared__ __align__(16) bf16 S[5][128*32];
    const int tid = threadIdx.x, lane = tid & 63, wid = tid >> 6;
    const int wr = wid >> 1, wc = wid & 1;
    const int lr = lane & 15, lg4 = lane >> 4;
    const int tr = tid >> 2;
    const int tc = ((tid & 3) ^ ((tid >> 3) & 3)) * 8;   // pre-swizzled src chunk
    const int co = (lg4 ^ ((lr >> 1) & 3)) * 8;          // swizzled read chunk
    int bid = blockIdx.x;
    bid = (bid & 7) * 64 + (bid >> 3);                   // XCD swizzle, 512 blocks
    const int bx = bid & 15, by = bid >> 4;              // 16 N-panels x 32 M-panels
    f32x4 accq[4][4], accv[4][4];
#pragma unroll
    for (int m = 0; m < 4; ++m)
#pragma unroll
        for (int n = 0; n < 4; ++n) { accq[m][n] = (f32x4)0.0f; accv[m][n] = (f32x4)0.0f; }
    for (int k0 = 0; k0 < K; k0 += 32) {
#pragma unroll
        for (int i = 0; i < 2; ++i) {
            size_t ga = (size_t)(by*128 + i*64 + tr)*K + k0 + tc;
            size_t gb = (size_t)(bx*128 + i*64 + tr)*K + k0 + tc;
            gl_lds16(Ah   + ga, &S[0][(i*256 + wid*64)*8]);
            gl_lds16(Al   + ga, &S[1][(i*256 + wid*64)*8]);
            gl_lds16(Bh   + gb, &S[2][(i*256 + wid*64)*8]);
            gl_lds16(Bl   + gb, &S[3][(i*256 + wid*64)*8]);
            gl_lds16(BTvg + gb, &S[4][(i*256 + wid*64)*8]);
        }
        __syncthreads();
        bf16x8 ah[4], al[4], bh[4], bl[4], bv[4];
#pragma unroll
        for (int m = 0; m < 4; ++m) {
            int o = (wr*64 + m*16 + lr)*32 + co;
            ah[m] = *(const bf16x8*)&S[0][o];
            al[m] = *(const bf16x8*)&S[1][o];
        }
#pragma unroll
        for (int n = 0; n < 4; ++n) {
            int o = (wc*64 + n*16 + lr)*32 + co;
            bh[n] = *(const bf16x8*)&S[2][o];
            bl[n] = *(const bf16x8*)&S[3][o];
            bv[n] = *(const bf16x8*)&S[4][o];
        }
#pragma unroll
        for (int m = 0; m < 4; ++m)
#pragma unroll
            for (int n = 0; n < 4; ++n) {
                accq[m][n] = __builtin_amdgcn_mfma_f32_16x16x32_bf16(al[m], bh[n], accq[m][n], 0, 0, 0);
                accq[m][n] = __builtin_amdgcn_mfma_f32_16x16x32_bf16(ah[m], bl[n], accq[m][n], 0, 0, 0);
                accq[m][n] = __builtin_amdgcn_mfma_f32_16x16x32_bf16(ah[m], bh[n], accq[m][n], 0, 0, 0);
                accv[m][n] = __builtin_amdgcn_mfma_f32_16x16x32_bf16(ah[m], bv[n], accv[m][n], 0, 0, 0);
            }
        __syncthreads();
    }
    // ---------------- qk epilogue: L2-norm + hi/lo split ----------------
    {
        const int headg = bx*2 + wc;                 // 0..31
        bf16* dh = (headg < 16) ? qhb : khb;
        bf16* dl = (headg < 16) ? qlb : klb;
        const int h = headg & 15;
#pragma unroll
        for (int m = 0; m < 4; ++m)
#pragma unroll
            for (int r = 0; r < 4; ++r) {
                float ss = accq[m][0][r]*accq[m][0][r] + accq[m][1][r]*accq[m][1][r]
                         + accq[m][2][r]*accq[m][2][r] + accq[m][3][r]*accq[m][3][r];
#pragma unroll
                for (int off = 1; off < 16; off <<= 1) ss += __shfl_xor(ss, off, 64);
                float sc = 1.0f / fmaxf(sqrtf(ss), 1e-12f);
                int token = by*128 + wr*64 + m*16 + lg4*4 + r;
#pragma unroll
                for (int n = 0; n < 4; ++n) {
                    int d = n*16 + lr;
                    float qv = accq[m][n][r] * sc;
                    bf16 hv = (bf16)qv;
                    size_t idx = ((size_t)token*H_ + h)*64 + d;
                    dh[idx] = hv;
                    dl[idx] = (bf16)(qv - (float)hv);
                }
            }
    }
    // ---------------- vg epilogue: transposed-V / silu-G ----------------
    {
        const int colbase = bx*128 + wc*64;
        const int b = by >> 4;
        if (colbase < 1024) {
            const int head = colbase >> 6;
#pragma unroll
            for (int m = 0; m < 4; ++m) {
                int trow = by*128 + wr*64 + m*16 + lg4*4;
                int tloc = trow - b*T_;
#pragma unroll
                for (int n = 0; n < 4; ++n) {
                    int d = n*16 + lr;
                    bf16x4 pk;
                    pk[0] = (bf16)accv[m][n][0]; pk[1] = (bf16)accv[m][n][1];
                    pk[2] = (bf16)accv[m][n][2]; pk[3] = (bf16)accv[m][n][3];
                    *(bf16x4*)(vt + ((size_t)((b*H_ + head)*64 + d))*T_ + tloc) = pk;
                }
            }
        } else {
#pragma unroll
            for (int m = 0; m < 4; ++m)
#pragma unroll
                for (int r = 0; r < 4; ++r) {
                    int token = by*128 + wr*64 + m*16 + lg4*4 + r;
#pragma unroll
                    for (int n = 0; n < 4; ++n) {
                        int colg = colbase - 1024 + n*16 + lr;
                        float g = accv[m][n][r];
                        Gf[(size_t)token*E_ + colg] = g / (1.0f + __expf(-g));
                    }
                }
        }
    }
}

// ---- output GEMM: out f32 = Yb bf16 @ WoT, 128x64 tile, swizzled LDS ----
__global__ __launch_bounds__(256) void gemm_out_kernel(
    const bf16* __restrict__ A, const bf16* __restrict__ BT, float* __restrict__ C) {
    const int K = E_, N = E_;
    __shared__ __align__(16) bf16 As[128*32];
    __shared__ __align__(16) bf16 Bs[64*32];
    int bid = blockIdx.x;
    bid = (bid & 7) * 64 + (bid >> 3);           // XCD swizzle, 512 blocks
    const int bx = bid & 15, by = bid >> 4;      // nbx = 1024/64 = 16
    const int tid = threadIdx.x, lane = tid & 63, wid = tid >> 6;
    const int wr = wid >> 1, wc = wid & 1;       // waves 64x32
    const int lr = lane & 15, lg4 = lane >> 4;
    f32x4 acc[4][2];
#pragma unroll
    for (int m = 0; m < 4; ++m)
#pragma unroll
        for (int n = 0; n < 2; ++n) acc[m][n] = (f32x4)0.0f;
    const int tr = tid >> 2;
    const int tc = ((tid & 3) ^ ((tid >> 3) & 3)) * 8;
    const int co = (lg4 ^ ((lr >> 1) & 3)) * 8;
    for (int k0 = 0; k0 < K; k0 += 32) {
#pragma unroll
        for (int i = 0; i < 2; ++i)
            gl_lds16(A + (size_t)(by*128 + i*64 + tr)*K + k0 + tc, &As[(i*256 + wid*64)*8]);
        gl_lds16(BT + (size_t)(bx*64 + tr)*K + k0 + tc, &Bs[(wid*64)*8]);
        __syncthreads();
        bf16x8 af[4], bfr[2];
#pragma unroll
        for (int m = 0; m < 4; ++m)
            af[m] = *(const bf16x8*)&As[(wr*64 + m*16 + lr)*32 + co];
#pragma unroll
        for (int n = 0; n < 2; ++n)
            bfr[n] = *(const bf16x8*)&Bs[(wc*32 + n*16 + lr)*32 + co];
#pragma unroll
        for (int m = 0; m < 4; ++m)
#pragma unroll
            for (int n = 0; n < 2; ++n)
                acc[m][n] = __builtin_amdgcn_mfma_f32_16x16x32_bf16(af[m], bfr[n], acc[m][n], 0, 0, 0);
        __syncthreads();
    }
    const int crow = by*128 + wr*64;
    const int ccol = bx*64 + wc*32 + lr;
#pragma unroll
    for (int m = 0; m < 4; ++m)
#pragma unroll
        for (int r = 0; r < 4; ++r) {
            int row = crow + m*16 + lg4*4 + r;
#pragma unroll
            for (int n = 0; n < 2; ++n)
                C[(size_t)row*N + ccol + n*16] = acc[m][n][r];
        }
}

// ---- decay attention: QBLK=128, dbuf prefetch, decay-reach jt skip ----
__global__ __launch_bounds__(256) void attn_kernel(
    const bf16* __restrict__ qh, const bf16* __restrict__ ql,
    const bf16* __restrict__ kh, const bf16* __restrict__ kl,
    const bf16* __restrict__ vt, const double* __restrict__ cl,
    const float* __restrict__ Gf, const float* __restrict__ rms_w,
    bf16* __restrict__ Y) {
    __shared__ __align__(16) bf16 Ksh[2][64*64];  // [key][d] swizzled, ping-pong
    __shared__ __align__(16) bf16 Ksl[2][64*64];
    __shared__ __align__(16) bf16 Vs[2][64*64];   // [d][key] swizzled, ping-pong
    __shared__ __align__(16) bf16 Ps[128*64];     // [qrow][key] swizzled
    const int rank = blockIdx.x >> 5, bh = blockIdx.x & 31;
    const int it = (rank < 8) ? (15 - rank) : (rank - 8);
    const int b = bh >> 4, h = bh & 15;
    const int tid = threadIdx.x, lane = tid & 63, wid = tid >> 6;
    const int i0 = it * 128;
    const int lr = lane & 15, lg4 = lane >> 4;
    bf16x8 qfh[2][2], qfl[2][2];
#pragma unroll
    for (int mm = 0; mm < 2; ++mm) {
        int qtok = i0 + wid*32 + mm*16 + lr;
        size_t qa = (size_t)(b*T_ + qtok)*E_ + h*64 + lg4*8;
        qfh[mm][0] = *(const bf16x8*)(qh + qa);
        qfh[mm][1] = *(const bf16x8*)(qh + qa + 32);
        qfl[mm][0] = *(const bf16x8*)(ql + qa);
        qfl[mm][1] = *(const bf16x8*)(ql + qa + 32);
    }
    const double* clrow = cl + (size_t)bh*T_;
    const double base = clrow[i0];
    float cli2[2][4];
#pragma unroll
    for (int mm = 0; mm < 2; ++mm)
#pragma unroll
        for (int r = 0; r < 4; ++r)
            cli2[mm][r] = (float)(clrow[i0 + wid*32 + mm*16 + lg4*4 + r] - base);
    f32x4 oacc[2][4];
#pragma unroll
    for (int mm = 0; mm < 2; ++mm)
#pragma unroll
        for (int n = 0; n < 4; ++n) oacc[mm][n] = (f32x4)0.0f;
    const int srow8 = lane >> 3;
    const int csrc  = (lane & 7) ^ srow8;
    auto STAGE = [&](int jt, int buf) {
        const int j0 = jt * 64;
#pragma unroll
        for (int i = 0; i < 2; ++i) {
            int krow = j0 + i*32 + wid*8 + srow8;
            int drow = i*32 + wid*8 + srow8;
            size_t gk = (size_t)(b*T_ + krow)*E_ + h*64 + csrc*8;
            gl_lds16(kh + gk, &Ksh[buf][(i*32 + wid*8)*64]);
            gl_lds16(kl + gk, &Ksl[buf][(i*32 + wid*8)*64]);
            gl_lds16(vt + (size_t)(bh*64 + drow)*T_ + j0 + csrc*8, &Vs[buf][(i*32 + wid*8)*64]);
        }
    };
    const int niter = 2*it + 2;
    int jt_min;
    {
        int lo = 0, hi = niter - 1;
        while (lo < hi) {
            int mid = (lo + hi) >> 1;
            int jend = mid*64 + 63; if (jend > i0) jend = i0;
            if (clrow[jend] <= base + 95.0) hi = mid; else lo = mid + 1;
        }
        jt_min = lo;
    }
    STAGE(jt_min, 0);
    __syncthreads();
    int cur = 0;
    for (int jt = jt_min; jt < niter; ++jt) {
        const int j0 = jt * 64;
        if (jt + 1 < niter) STAGE(jt + 1, cur ^ 1);
#pragma unroll
        for (int n = 0; n < 4; ++n) {
            const int r = n*16 + lr;
            const int sw = r & 7;
            const int ko = r*64;
            bf16x8 k_h0 = *(const bf16x8*)&Ksh[cur][ko + ((lg4 ^ sw)*8)];
            bf16x8 k_h1 = *(const bf16x8*)&Ksh[cur][ko + (((lg4+4) ^ sw)*8)];
            bf16x8 k_l0 = *(const bf16x8*)&Ksl[cur][ko + ((lg4 ^ sw)*8)];
            bf16x8 k_l1 = *(const bf16x8*)&Ksl[cur][ko + (((lg4+4) ^ sw)*8)];
            const int j = j0 + r;
            const float cj = (float)(clrow[j] - base);
#pragma unroll
            for (int mm = 0; mm < 2; ++mm) {
                f32x4 s = (f32x4)0.0f;
                __builtin_amdgcn_s_setprio(1);
                s = __builtin_amdgcn_mfma_f32_16x16x32_bf16(qfl[mm][0], k_h0, s, 0, 0, 0);
                s = __builtin_amdgcn_mfma_f32_16x16x32_bf16(qfl[mm][1], k_h1, s, 0, 0, 0);
                s = __builtin_amdgcn_mfma_f32_16x16x32_bf16(qfh[mm][0], k_l0, s, 0, 0, 0);
                s = __builtin_amdgcn_mfma_f32_16x16x32_bf16(qfh[mm][1], k_l1, s, 0, 0, 0);
                s = __builtin_amdgcn_mfma_f32_16x16x32_bf16(qfh[mm][0], k_h0, s, 0, 0, 0);
                s = __builtin_amdgcn_mfma_f32_16x16x32_bf16(qfh[mm][1], k_h1, s, 0, 0, 0);
                __builtin_amdgcn_s_setprio(0);
                const int prbase = wid*32 + mm*16 + lg4*4;
#pragma unroll
                for (int r4 = 0; r4 < 4; ++r4) {
                    const int pr = prbase + r4;
                    const int qrow = i0 + pr;
                    float val = (j <= qrow)
                        ? s[r4] * __expf(cli2[mm][r4] - cj) : 0.0f;
                    const int cw = n*2 + (lr >> 3);
                    Ps[pr*64 + ((cw ^ (pr & 7))*8) + (lane & 7)] = (bf16)val;
                }
            }
        }
#pragma unroll
        for (int kk = 0; kk < 2; ++kk) {
            const int js = kk*4 + lg4;
            bf16x8 pf[2];
#pragma unroll
            for (int mm = 0; mm < 2; ++mm) {
                const int rp = wid*32 + mm*16 + lr;
                pf[mm] = *(const bf16x8*)&Ps[rp*64 + ((js ^ (rp & 7))*8)];
            }
            __builtin_amdgcn_s_setprio(1);
#pragma unroll
            for (int n = 0; n < 4; ++n) {
                const int rv = n*16 + lr;
                bf16x8 vf = *(const bf16x8*)&Vs[cur][rv*64 + ((js ^ (rv & 7))*8)];
                oacc[0][n] = __builtin_amdgcn_mfma_f32_16x16x32_bf16(pf[0], vf, oacc[0][n], 0, 0, 0);
                oacc[1][n] = __builtin_amdgcn_mfma_f32_16x16x32_bf16(pf[1], vf, oacc[1][n], 0, 0, 0);
            }
            __builtin_amdgcn_s_setprio(0);
        }
        __syncthreads();
        cur ^= 1;
    }
#pragma unroll
    for (int mm = 0; mm < 2; ++mm)
#pragma unroll
        for (int r = 0; r < 4; ++r) {
            float ss = oacc[mm][0][r]*oacc[mm][0][r] + oacc[mm][1][r]*oacc[mm][1][r]
                     + oacc[mm][2][r]*oacc[mm][2][r] + oacc[mm][3][r]*oacc[mm][3][r];
#pragma unroll
            for (int off = 1; off < 16; off <<= 1) ss += __shfl_xor(ss, off, 64);
            const float scale = rsqrtf(ss * (1.0f/64.0f) + 1e-6f);
            const int gtok = b*T_ + i0 + wid*32 + mm*16 + lg4*4 + r;
#pragma unroll
            for (int n = 0; n < 4; ++n) {
                const int d = n*16 + lr;
                float o = oacc[mm][n][r] * scale * rms_w[d];
                float gate = Gf[(size_t)gtok*E_ + h*64 + d];
                Y[(size_t)gtok*E_ + h*64 + d] = (bf16)(o * gate);
            }
        }
}

extern "C" void kernel_launch(void* const* d_in, const int* in_sizes, int n_in,
                              void* d_out, int out_size, void* d_ws, size_t ws_size,
                              hipStream_t stream) {
    const float* x       = (const float*)d_in[0];
    const float* Wq      = (const float*)d_in[1];
    const float* Wk      = (const float*)d_in[2];
    const float* Wv      = (const float*)d_in[3];
    const float* Wa      = (const float*)d_in[4];
    const float* Wg      = (const float*)d_in[5];
    const float* Wo      = (const float*)d_in[6];
    const float* A_log   = (const float*)d_in[7];
    const float* dt_bias = (const float*)d_in[8];
    const float* rms_w   = (const float*)d_in[9];
    float* out = (float*)d_out;

    char* w = (char*)d_ws;
    size_t off = 0;
    auto alloc = [&](size_t bytes) {
        void* p = w + off; off += (bytes + 255) & ~(size_t)255; return p;
    };
    bf16*   xh   = (bf16*)  alloc((size_t)MTOK*E_*2);
    bf16*   xl   = (bf16*)  alloc((size_t)MTOK*E_*2);
    bf16*   WTqh = (bf16*)  alloc((size_t)2048*E_*2);
    bf16*   WTql = (bf16*)  alloc((size_t)2048*E_*2);
    bf16*   WTvg = (bf16*)  alloc((size_t)2048*E_*2);
    bf16*   WTo  = (bf16*)  alloc((size_t)E_*E_*2);
    bf16*   qhb  = (bf16*)  alloc((size_t)MTOK*E_*2);
    bf16*   qlb  = (bf16*)  alloc((size_t)MTOK*E_*2);
    bf16*   khb  = (bf16*)  alloc((size_t)MTOK*E_*2);
    bf16*   klb  = (bf16*)  alloc((size_t)MTOK*E_*2);
    bf16*   vt   = (bf16*)  alloc((size_t)MTOK*E_*2);
    float*  Gf   = (float*) alloc((size_t)MTOK*E_*4);
    float*  lg   = (float*) alloc((size_t)B_*H_*T_*4);
    double* cl   = (double*)alloc((size_t)B_*H_*T_*8);
    bf16*   Yb   = (bf16*)  alloc((size_t)MTOK*E_*2);
    float*  WaT  = (float*) alloc((size_t)H_*E_*4);

    // weight prep (incl. WaT as seg 5)
    hipLaunchKernelGGL(prep_weights_kernel, dim3(5184), dim3(32, 8), 0, stream,
                       Wq, Wk, Wv, Wg, Wo, Wa, WTqh, WTql, WTvg, WTo, WaT);

    hipLaunchKernelGGL(dtx_kernel, dim3(256), dim3(256), 0, stream,
                       x, WaT, A_log, dt_bias, lg, xh, xl);
    hipLaunchKernelGGL(scan_kernel, dim3(B_*H_), dim3(256), 0, stream, lg, cl);

    // fused projection GEMMs (each block: one qk tile + one vg tile)
    hipLaunchKernelGGL(gemm_qkvg_kernel, dim3(512), dim3(256), 0, stream,
                       xh, xl, WTqh, WTql, WTvg, qhb, qlb, khb, klb, vt, Gf);

    // attention + RMSNorm + gate
    hipLaunchKernelGGL(attn_kernel, dim3(512), dim3(256), 0, stream,
                       qhb, qlb, khb, klb, vt, cl, Gf, rms_w, Yb);

    // output projection
    hipLaunchKernelGGL(gemm_out_kernel, dim3(512), dim3(256), 0, stream, Yb, WTo, out);
}